// Round 1
// baseline (1326.858 us; speedup 1.0000x reference)
//
#include <hip/hip_runtime.h>
#include <math.h>

constexpr int NN = 10000;
constexpr int EE = 320000;
constexpr int H  = 4;
constexpr int D  = 64;
constexpr int C  = 16;
constexpr int IN = 256;
constexpr int HD = H * D; // 256

// ---- workspace layout (float offsets) ----
constexpr long OFF_FEAT = 0;                              // N*HD
constexpr long OFF_EW   = OFF_FEAT + (long)NN * HD;       // E*H
constexpr long OFF_EL   = OFF_EW   + (long)EE * H;        // N*H
constexpr long OFF_ER   = OFF_EL   + (long)NN * H;        // N*H
constexpr long OFF_F1   = OFF_ER   + (long)NN * H;        // N*H
constexpr long OFF_F2   = OFF_F1   + (long)NN * H;        // N*H
constexpr long OFF_GATE = OFF_F2   + (long)NN * H;        // N*H
constexpr long OFF_PRED = OFF_GATE + (long)NN * H;        // N ints
// zeroed accumulator block starts here:
constexpr long OFF_ZERO = OFF_PRED + (long)NN;
constexpr long OFF_AGG  = OFF_ZERO;                       // N*HD
constexpr long OFF_DEN  = OFF_AGG  + (long)NN * HD;       // N*H
constexpr long OFF_F1S  = OFF_DEN  + (long)NN * H;        // N*H
constexpr long OFF_CNT  = OFF_F1S  + (long)NN * H;        // N*H*C
constexpr long OFF_DEG  = OFF_CNT  + (long)NN * H * C;    // N
constexpr long OFF_SUM  = OFF_DEG  + (long)NN;            // 8 (s1,q1,s2,q2,...)
constexpr long OFF_PRES = OFF_SUM  + 8;                   // C flags as float
constexpr long WS_FLOATS= OFF_PRES + C;

__global__ __launch_bounds__(256) void k_pred(const float* __restrict__ logits,
                                              int* __restrict__ pred) {
    int n = blockIdx.x * 256 + threadIdx.x;
    if (n >= NN) return;
    const float* row = logits + (long)n * C;
    float best = row[0]; int bi = 0;
#pragma unroll
    for (int c = 1; c < C; ++c) { float v = row[c]; if (v > best) { best = v; bi = c; } }
    pred[n] = bi;
}

__global__ __launch_bounds__(256) void k_deg(const int* __restrict__ dst,
                                             float* __restrict__ degs) {
    int e = blockIdx.x * 256 + threadIdx.x;
    if (e >= EE) return;
    atomicAdd(&degs[dst[e]], 1.0f);
}

// fused: feat = h @ Wfc ; el/er = sum_d feat*attn
// block = 256 threads (thread t owns output column t), 16 nodes per block
__global__ __launch_bounds__(256) void k_gemm(const float* __restrict__ hin,
                                              const float* __restrict__ W,
                                              const float* __restrict__ al,
                                              const float* __restrict__ ar,
                                              float* __restrict__ feat,
                                              float* __restrict__ el,
                                              float* __restrict__ er) {
    __shared__ float hh[16][IN];
    int t = threadIdx.x;
    int n0 = blockIdx.x * 16;
#pragma unroll
    for (int i = 0; i < 16; ++i) hh[i][t] = hin[(long)(n0 + i) * IN + t];
    __syncthreads();

    float acc[16];
#pragma unroll
    for (int i = 0; i < 16; ++i) acc[i] = 0.f;
    for (int k = 0; k < IN; ++k) {
        float w = W[(long)k * HD + t];
#pragma unroll
        for (int i = 0; i < 16; ++i) acc[i] = fmaf(hh[i][k], w, acc[i]);
    }
#pragma unroll
    for (int i = 0; i < 16; ++i) feat[(long)(n0 + i) * HD + t] = acc[i];

    // el/er: wave h = t>>6 owns columns of head h (t = h*64 + d)
    float aL = al[t], aR = ar[t];
    int hidx = t >> 6;
#pragma unroll
    for (int i = 0; i < 16; ++i) {
        float vl = acc[i] * aL;
        float vr = acc[i] * aR;
        for (int off = 32; off; off >>= 1) {
            vl += __shfl_down(vl, off);
            vr += __shfl_down(vr, off);
        }
        if ((t & 63) == 0) {
            el[(long)(n0 + i) * H + hidx] = vl;
            er[(long)(n0 + i) * H + hidx] = vr;
        }
    }
}

// edge pass 1: ew = exp(leaky(el[src]+er[dst])), denom[dst] += ew
// (segment_max dropped: exp(e)/sum(exp(e)) == softmax exactly; |e| is small)
__global__ __launch_bounds__(256) void k_edge1(const int* __restrict__ src,
                                               const int* __restrict__ dst,
                                               const float* __restrict__ el,
                                               const float* __restrict__ er,
                                               float* __restrict__ ew,
                                               float* __restrict__ den) {
    int e = blockIdx.x * 256 + threadIdx.x;
    if (e >= EE) return;
    int s = src[e], d = dst[e];
    float4 L = *(const float4*)(el + (long)s * H);
    float4 R = *(const float4*)(er + (long)d * H);
    float4 w;
    float x;
    x = L.x + R.x; x = x > 0.f ? x : 0.2f * x; w.x = expf(x);
    x = L.y + R.y; x = x > 0.f ? x : 0.2f * x; w.y = expf(x);
    x = L.z + R.z; x = x > 0.f ? x : 0.2f * x; w.z = expf(x);
    x = L.w + R.w; x = x > 0.f ? x : 0.2f * x; w.w = expf(x);
    *(float4*)(ew + (long)e * H) = w;
    float* dn = den + (long)d * H;
    atomicAdd(dn + 0, w.x);
    atomicAdd(dn + 1, w.y);
    atomicAdd(dn + 2, w.z);
    atomicAdd(dn + 3, w.w);
}

// edge pass 2: one wave per edge. a = ew/den[dst]; agg[dst] += a*feat[src];
// f1sum/cnts atomics on lanes 0..3; present flag.
__global__ __launch_bounds__(256) void k_edge2(const int* __restrict__ src,
                                               const int* __restrict__ dst,
                                               const float* __restrict__ ew,
                                               const float* __restrict__ den,
                                               const float* __restrict__ feat,
                                               const int* __restrict__ pred,
                                               float* __restrict__ agg,
                                               float* __restrict__ f1s,
                                               float* __restrict__ cnt,
                                               float* __restrict__ pres) {
    int wid = blockIdx.x * 4 + (threadIdx.x >> 6);
    int lane = threadIdx.x & 63;
    if (wid >= EE) return;
    int s = src[wid], d = dst[wid];
    float4 w  = *(const float4*)(ew + (long)wid * H);
    float4 dn = *(const float4*)(den + (long)d * H);
    float a0 = w.x / dn.x, a1 = w.y / dn.y, a2 = w.z / dn.z, a3 = w.w / dn.w;

    float4 f = *(const float4*)(feat + (long)s * HD + lane * 4);
    int hidx = lane >> 4;
    float a = (hidx == 0) ? a0 : (hidx == 1) ? a1 : (hidx == 2) ? a2 : a3;
    float* ap = agg + (long)d * HD + lane * 4;
    atomicAdd(ap + 0, a * f.x);
    atomicAdd(ap + 1, a * f.y);
    atomicAdd(ap + 2, a * f.z);
    atomicAdd(ap + 3, a * f.w);

    if (lane < H) {
        int ps = pred[s], pd = pred[d];
        float ah = (lane == 0) ? a0 : (lane == 1) ? a1 : (lane == 2) ? a2 : a3;
        if (ps == pd) atomicAdd(&f1s[(long)d * H + lane], ah);
        atomicAdd(&cnt[((long)d * H + lane) * C + ps], ah);
        if (lane == 0) pres[ps] = 1.0f; // benign race, same value
    }
}

// per-(n,h): f1, f2, and global sum/sumsq for the joint layernorm
__global__ __launch_bounds__(256) void k_f(const float* __restrict__ f1s,
                                           const float* __restrict__ cnt,
                                           const float* __restrict__ degs,
                                           const float* __restrict__ pres,
                                           float* __restrict__ f1,
                                           float* __restrict__ f2,
                                           float* __restrict__ sums) {
    int t = blockIdx.x * 256 + threadIdx.x;
    float f1v = 0.f, f2v = 0.f;
    if (t < NN * H) {
        int n = t >> 2;
        float deg = fmaxf(degs[n], 1.0f);
        float inv = 1.0f / deg;
        f1v = f1s[t] * inv;
        const float* cr = cnt + (long)t * C;
#pragma unroll
        for (int c = 0; c < C; ++c) {
            float v = fmaxf(cr[c] * inv, 1e-5f);
            if (pres[c] > 0.5f) f2v -= v * logf(v);
        }
        f1[t] = f1v;
        f2[t] = f2v;
    }
    // wave reduction (40000 % 64 == 0, so waves are uniformly valid/invalid)
    float s1 = f1v, q1 = f1v * f1v, s2 = f2v, q2 = f2v * f2v;
    for (int off = 32; off; off >>= 1) {
        s1 += __shfl_down(s1, off);
        q1 += __shfl_down(q1, off);
        s2 += __shfl_down(s2, off);
        q2 += __shfl_down(q2, off);
    }
    if ((threadIdx.x & 63) == 0 && t < NN * H) {
        atomicAdd(&sums[0], s1);
        atomicAdd(&sums[1], q1);
        atomicAdd(&sums[2], s2);
        atomicAdd(&sums[3], q2);
    }
}

__global__ __launch_bounds__(256) void k_z(const float* __restrict__ f1,
                                           const float* __restrict__ f2,
                                           const float* __restrict__ sums,
                                           const float* __restrict__ old_z,
                                           const float* __restrict__ tau1,
                                           const float* __restrict__ tau2,
                                           float* __restrict__ zout,
                                           float* __restrict__ gate) {
    int t = blockIdx.x * 256 + threadIdx.x;
    if (t >= NN * H) return;
    constexpr float inv = 1.0f / (NN * H);
    float mu1 = sums[0] * inv, mu2 = sums[2] * inv;
    float v1 = fmaxf(sums[1] * inv - mu1 * mu1, 0.f);
    float v2 = fmaxf(sums[3] * inv - mu2 * mu2, 0.f);
    float r1 = rsqrtf(v1 + 1e-5f), r2 = rsqrtf(v2 + 1e-5f);
    float nf1 = (f1[t] - mu1) * r1;
    float nf2 = (f2[t] - mu2) * r2;
    // sigmoid(tau - nf) = 1/(1+exp(nf-tau))
    float z = (1.f / (1.f + expf(nf1 - tau1[0]))) * (1.f / (1.f + expf(nf2 - tau2[0])));
    zout[t] = z;
    gate[t] = fminf(old_z[t], z);
}

__global__ __launch_bounds__(256) void k_out(const float* __restrict__ feat,
                                             const float* __restrict__ agg,
                                             const float* __restrict__ gate,
                                             const float* __restrict__ degs,
                                             float* __restrict__ out) {
    long i = (long)blockIdx.x * 256 + threadIdx.x;
    if (i >= (long)NN * HD) return;
    int n = (int)(i >> 8);
    int h = (int)((i >> 6) & 3);
    float nrm = rsqrtf(fmaxf(degs[n], 1.f)); // degs clamped >=1, ^-0.5
    out[i] = feat[i] + gate[n * H + h] * agg[i] * nrm;
}

extern "C" void kernel_launch(void* const* d_in, const int* in_sizes, int n_in,
                              void* d_out, int out_size, void* d_ws, size_t ws_size,
                              hipStream_t stream) {
    const float* hin    = (const float*)d_in[0];
    const float* logits = (const float*)d_in[1];
    const float* old_z  = (const float*)d_in[2];
    const float* attn_l = (const float*)d_in[3];
    const float* attn_r = (const float*)d_in[4];
    const float* Wfc    = (const float*)d_in[5];
    const float* tau1   = (const float*)d_in[6];
    const float* tau2   = (const float*)d_in[7];
    const int*   src    = (const int*)d_in[8];
    const int*   dst    = (const int*)d_in[9];
    float* out = (float*)d_out;
    float* ws  = (float*)d_ws;

    int* pred = (int*)(ws + OFF_PRED);

    // zero the accumulator block every call (ws is not re-poisoned between replays)
    hipMemsetAsync(ws + OFF_ZERO, 0, (size_t)(WS_FLOATS - OFF_ZERO) * sizeof(float), stream);

    k_pred <<<(NN + 255) / 256, 256, 0, stream>>>(logits, pred);
    k_deg  <<<(EE + 255) / 256, 256, 0, stream>>>(dst, ws + OFF_DEG);
    k_gemm <<<NN / 16, 256, 0, stream>>>(hin, Wfc, attn_l, attn_r,
                                         ws + OFF_FEAT, ws + OFF_EL, ws + OFF_ER);
    k_edge1<<<(EE + 255) / 256, 256, 0, stream>>>(src, dst, ws + OFF_EL, ws + OFF_ER,
                                                  ws + OFF_EW, ws + OFF_DEN);
    k_edge2<<<EE / 4, 256, 0, stream>>>(src, dst, ws + OFF_EW, ws + OFF_DEN,
                                        ws + OFF_FEAT, pred,
                                        ws + OFF_AGG, ws + OFF_F1S, ws + OFF_CNT,
                                        ws + OFF_PRES);
    k_f    <<<(NN * H + 255) / 256, 256, 0, stream>>>(ws + OFF_F1S, ws + OFF_CNT,
                                                      ws + OFF_DEG, ws + OFF_PRES,
                                                      ws + OFF_F1, ws + OFF_F2,
                                                      ws + OFF_SUM);
    k_z    <<<(NN * H + 255) / 256, 256, 0, stream>>>(ws + OFF_F1, ws + OFF_F2,
                                                      ws + OFF_SUM, old_z, tau1, tau2,
                                                      out + (long)NN * HD, ws + OFF_GATE);
    k_out  <<<(NN * HD + 255) / 256, 256, 0, stream>>>(ws + OFF_FEAT, ws + OFF_AGG,
                                                       ws + OFF_GATE, ws + OFF_DEG, out);
}

// Round 4
// 230.996 us; speedup vs baseline: 5.7441x; 5.7441x over previous
//
#include <hip/hip_runtime.h>
#include <math.h>

constexpr int NN = 10000;
constexpr int EE = 320000;
constexpr int H  = 4;
constexpr int D  = 64;
constexpr int C  = 16;
constexpr int IN = 256;
constexpr int HD = H * D; // 256

// ---- workspace layout (float-element offsets) ----
constexpr long OFF_FEAT = 0;                               // N*HD f32
constexpr long OFF_EL   = OFF_FEAT + (long)NN * HD;        // N*H
constexpr long OFF_ER   = OFF_EL   + (long)NN * H;         // N*H
constexpr long OFF_F1   = OFF_ER   + (long)NN * H;         // N*H
constexpr long OFF_F2   = OFF_F1   + (long)NN * H;         // N*H
constexpr long OFF_GATE = OFF_F2   + (long)NN * H;         // N*H
constexpr long OFF_F1S  = OFF_GATE + (long)NN * H;         // N*H
constexpr long OFF_CNT  = OFF_F1S  + (long)NN * H;         // N*H*C
constexpr long OFF_AGG  = OFF_CNT  + (long)NN * H * C;     // N*HD
constexpr long OFF_PRED = OFF_AGG  + (long)NN * HD;        // N   (int)
constexpr long OFF_SSRC = OFF_PRED + (long)NN;             // E   (int) src sorted by dst
constexpr long OFF_ROWP = OFF_SSRC + (long)EE;             // N+1 (int)
constexpr long OFF_CURS = OFF_ROWP + (long)NN + 1;         // N   (int)
// zeroed-every-call block:
constexpr long OFF_ZERO = OFF_CURS + (long)NN;
constexpr long OFF_DEGI = OFF_ZERO;                        // N   (int)
constexpr long OFF_SUM  = OFF_DEGI + (long)NN;             // 8 f32 (s1,q1,s2,q2)
constexpr long OFF_PRES = OFF_SUM  + 8;                    // 1 int bitmask
constexpr long WS_END   = OFF_PRES + 1;

__global__ __launch_bounds__(256) void k_pred(const float* __restrict__ logits,
                                              int* __restrict__ pred) {
    int n = blockIdx.x * 256 + threadIdx.x;
    if (n >= NN) return;
    const float* row = logits + (long)n * C;
    float best = row[0]; int bi = 0;
#pragma unroll
    for (int c = 1; c < C; ++c) { float v = row[c]; if (v > best) { best = v; bi = c; } }
    pred[n] = bi;
}

__global__ __launch_bounds__(256) void k_count(const int* __restrict__ dst,
                                               int* __restrict__ deg_i) {
    int e = blockIdx.x * 256 + threadIdx.x;
    if (e >= EE) return;
    atomicAdd(&deg_i[dst[e]], 1);
}

// single-block exclusive scan of deg_i[0..NN) -> rowptr[0..NN], cursor copy
__global__ __launch_bounds__(256) void k_scan(const int* __restrict__ deg_i,
                                              int* __restrict__ rowptr,
                                              int* __restrict__ cursor) {
    __shared__ int lsum[256];
    constexpr int CH = (NN + 255) / 256; // 40
    int t = threadIdx.x;
    int base = t * CH;
    int s = 0;
    for (int i = 0; i < CH; ++i) { int idx = base + i; if (idx < NN) s += deg_i[idx]; }
    lsum[t] = s;
    __syncthreads();
    for (int off = 1; off < 256; off <<= 1) {
        int v = (t >= off) ? lsum[t - off] : 0;
        __syncthreads();
        lsum[t] += v;
        __syncthreads();
    }
    int run = (t == 0) ? 0 : lsum[t - 1];
    for (int i = 0; i < CH; ++i) {
        int idx = base + i;
        if (idx < NN) { rowptr[idx] = run; cursor[idx] = run; run += deg_i[idx]; }
    }
    if (t == 255) rowptr[NN] = run; // == EE
}

__global__ __launch_bounds__(256) void k_scatter(const int* __restrict__ src,
                                                 const int* __restrict__ dst,
                                                 int* __restrict__ cursor,
                                                 int* __restrict__ ssrc) {
    int e = blockIdx.x * 256 + threadIdx.x;
    if (e >= EE) return;
    int d = dst[e];
    int pos = atomicAdd(&cursor[d], 1);
    ssrc[pos] = src[e];
}

// fused: feat = h @ Wfc ; el/er = sum_d feat*attn
__global__ __launch_bounds__(256) void k_gemm(const float* __restrict__ hin,
                                              const float* __restrict__ W,
                                              const float* __restrict__ al,
                                              const float* __restrict__ ar,
                                              float* __restrict__ feat,
                                              float* __restrict__ el,
                                              float* __restrict__ er) {
    __shared__ float hh[16][IN];
    int t = threadIdx.x;
    int n0 = blockIdx.x * 16;
#pragma unroll
    for (int i = 0; i < 16; ++i) hh[i][t] = hin[(long)(n0 + i) * IN + t];
    __syncthreads();

    float acc[16];
#pragma unroll
    for (int i = 0; i < 16; ++i) acc[i] = 0.f;
    for (int k = 0; k < IN; ++k) {
        float w = W[(long)k * HD + t];
#pragma unroll
        for (int i = 0; i < 16; ++i) acc[i] = fmaf(hh[i][k], w, acc[i]);
    }
#pragma unroll
    for (int i = 0; i < 16; ++i) feat[(long)(n0 + i) * HD + t] = acc[i];

    float aL = al[t], aR = ar[t];
    int hidx = t >> 6;
#pragma unroll
    for (int i = 0; i < 16; ++i) {
        float vl = acc[i] * aL;
        float vr = acc[i] * aR;
        for (int off = 32; off; off >>= 1) {
            vl += __shfl_down(vl, off);
            vr += __shfl_down(vr, off);
        }
        if ((t & 63) == 0) {
            el[(long)(n0 + i) * H + hidx] = vl;
            er[(long)(n0 + i) * H + hidx] = vr;
        }
    }
}

// one wave per dst node: softmax-weighted aggregation + f1/cnt/present stats.
// Single pass with unnormalized weights (divide by denom at the end — exact).
__global__ __launch_bounds__(256) void k_agg(const int* __restrict__ rowptr,
                                             const int* __restrict__ ssrc,
                                             const float* __restrict__ el,
                                             const float* __restrict__ er,
                                             const float* __restrict__ feat,
                                             const int* __restrict__ pred,
                                             float* __restrict__ agg,
                                             float* __restrict__ f1s,
                                             float* __restrict__ cnt,
                                             int* __restrict__ presmask) {
    __shared__ int smask[4];
    int wv = threadIdx.x >> 6, lane = threadIdx.x & 63;
    int n = blockIdx.x * 4 + wv; // grid = NN/4 exactly
    int beg = rowptr[n], end = rowptr[n + 1];
    float4 R = *(const float4*)(er + (long)n * H);
    int pd = pred[n];
    int hidx = lane >> 4, cidx = lane & 15;

    float4 acc = {0.f, 0.f, 0.f, 0.f};
    float4 dsl = {0.f, 0.f, 0.f, 0.f};
    float ca = 0.f, f1a = 0.f;
    int mask = 0;

    for (int base = beg; base < end; base += 64) {
        int nk = end - base; if (nk > 64) nk = 64;
        int sl = 0, pl = -1;
        float4 w4 = {0.f, 0.f, 0.f, 0.f};
        if (lane < nk) {
            sl = ssrc[base + lane];
            pl = pred[sl];
            float4 L = *(const float4*)(el + (long)sl * H);
            float x;
            x = L.x + R.x; x = x > 0.f ? x : 0.2f * x; w4.x = __expf(x);
            x = L.y + R.y; x = x > 0.f ? x : 0.2f * x; w4.y = __expf(x);
            x = L.z + R.z; x = x > 0.f ? x : 0.2f * x; w4.z = __expf(x);
            x = L.w + R.w; x = x > 0.f ? x : 0.2f * x; w4.w = __expf(x);
            mask |= 1 << pl;
        }
        dsl.x += w4.x; dsl.y += w4.y; dsl.z += w4.z; dsl.w += w4.w;

        for (int k = 0; k < nk; ++k) {
            int s  = __shfl(sl, k);
            int ps = __shfl(pl, k);
            float w0 = __shfl(w4.x, k);
            float w1 = __shfl(w4.y, k);
            float w2 = __shfl(w4.z, k);
            float w3 = __shfl(w4.w, k);
            float wa = hidx == 0 ? w0 : hidx == 1 ? w1 : hidx == 2 ? w2 : w3;
            float4 f = *(const float4*)(feat + (long)s * HD + lane * 4);
            acc.x = fmaf(wa, f.x, acc.x);
            acc.y = fmaf(wa, f.y, acc.y);
            acc.z = fmaf(wa, f.z, acc.z);
            acc.w = fmaf(wa, f.w, acc.w);
            f1a += (ps == pd)   ? wa : 0.f;
            ca  += (ps == cidx) ? wa : 0.f;
        }
    }

    // wave-reduce denominators
    for (int off = 1; off < 64; off <<= 1) {
        dsl.x += __shfl_xor(dsl.x, off);
        dsl.y += __shfl_xor(dsl.y, off);
        dsl.z += __shfl_xor(dsl.z, off);
        dsl.w += __shfl_xor(dsl.w, off);
    }
    float inv0 = dsl.x > 0.f ? 1.f / dsl.x : 0.f;
    float inv1 = dsl.y > 0.f ? 1.f / dsl.y : 0.f;
    float inv2 = dsl.z > 0.f ? 1.f / dsl.z : 0.f;
    float inv3 = dsl.w > 0.f ? 1.f / dsl.w : 0.f;
    float invh = hidx == 0 ? inv0 : hidx == 1 ? inv1 : hidx == 2 ? inv2 : inv3;

    float4 o;
    o.x = acc.x * invh; o.y = acc.y * invh; o.z = acc.z * invh; o.w = acc.w * invh;
    *(float4*)(agg + (long)n * HD + lane * 4) = o;
    cnt[(long)n * (H * C) + lane] = ca * invh;
    if (cidx == 0) f1s[(long)n * H + hidx] = f1a * invh;

    for (int off = 1; off < 64; off <<= 1) mask |= __shfl_xor(mask, off);
    if (lane == 0) smask[wv] = mask;
    __syncthreads();
    if (threadIdx.x == 0)
        atomicOr(presmask, smask[0] | smask[1] | smask[2] | smask[3]);
}

// per-(n,h): f1, f2, and global sum/sumsq for the joint layernorm
__global__ __launch_bounds__(256) void k_f(const float* __restrict__ f1s,
                                           const float* __restrict__ cnt,
                                           const int* __restrict__ rowptr,
                                           const int* __restrict__ presmask,
                                           float* __restrict__ f1,
                                           float* __restrict__ f2,
                                           float* __restrict__ sums) {
    int t = blockIdx.x * 256 + threadIdx.x;
    int pm = *presmask;
    float f1v = 0.f, f2v = 0.f;
    if (t < NN * H) {
        int n = t >> 2;
        float deg = fmaxf((float)(rowptr[n + 1] - rowptr[n]), 1.0f);
        float inv = 1.0f / deg;
        f1v = f1s[t] * inv;
        const float* cr = cnt + (long)t * C;
#pragma unroll
        for (int c = 0; c < C; ++c) {
            float v = fmaxf(cr[c] * inv, 1e-5f);
            if ((pm >> c) & 1) f2v -= v * logf(v);
        }
        f1[t] = f1v;
        f2[t] = f2v;
    }
    float s1 = f1v, q1 = f1v * f1v, s2 = f2v, q2 = f2v * f2v;
    for (int off = 32; off; off >>= 1) {
        s1 += __shfl_down(s1, off);
        q1 += __shfl_down(q1, off);
        s2 += __shfl_down(s2, off);
        q2 += __shfl_down(q2, off);
    }
    if ((threadIdx.x & 63) == 0 && t < NN * H) {
        atomicAdd(&sums[0], s1);
        atomicAdd(&sums[1], q1);
        atomicAdd(&sums[2], s2);
        atomicAdd(&sums[3], q2);
    }
}

__global__ __launch_bounds__(256) void k_z(const float* __restrict__ f1,
                                           const float* __restrict__ f2,
                                           const float* __restrict__ sums,
                                           const float* __restrict__ old_z,
                                           const float* __restrict__ tau1,
                                           const float* __restrict__ tau2,
                                           float* __restrict__ zout,
                                           float* __restrict__ gate) {
    int t = blockIdx.x * 256 + threadIdx.x;
    if (t >= NN * H) return;
    constexpr float inv = 1.0f / (NN * H);
    float mu1 = sums[0] * inv, mu2 = sums[2] * inv;
    float v1 = fmaxf(sums[1] * inv - mu1 * mu1, 0.f);
    float v2 = fmaxf(sums[3] * inv - mu2 * mu2, 0.f);
    float r1 = rsqrtf(v1 + 1e-5f), r2 = rsqrtf(v2 + 1e-5f);
    float nf1 = (f1[t] - mu1) * r1;
    float nf2 = (f2[t] - mu2) * r2;
    float z = (1.f / (1.f + expf(nf1 - tau1[0]))) * (1.f / (1.f + expf(nf2 - tau2[0])));
    zout[t] = z;
    gate[t] = fminf(old_z[t], z);
}

__global__ __launch_bounds__(256) void k_out(const float* __restrict__ feat,
                                             const float* __restrict__ agg,
                                             const float* __restrict__ gate,
                                             const int* __restrict__ rowptr,
                                             float* __restrict__ out) {
    long i = (long)blockIdx.x * 256 + threadIdx.x;
    if (i >= (long)NN * HD) return;
    int n = (int)(i >> 8);
    int h = (int)((i >> 6) & 3);
    float deg = fmaxf((float)(rowptr[n + 1] - rowptr[n]), 1.f);
    float nrm = rsqrtf(deg);
    out[i] = feat[i] + gate[n * H + h] * agg[i] * nrm;
}

extern "C" void kernel_launch(void* const* d_in, const int* in_sizes, int n_in,
                              void* d_out, int out_size, void* d_ws, size_t ws_size,
                              hipStream_t stream) {
    const float* hin    = (const float*)d_in[0];
    const float* logits = (const float*)d_in[1];
    const float* old_z  = (const float*)d_in[2];
    const float* attn_l = (const float*)d_in[3];
    const float* attn_r = (const float*)d_in[4];
    const float* Wfc    = (const float*)d_in[5];
    const float* tau1   = (const float*)d_in[6];
    const float* tau2   = (const float*)d_in[7];
    const int*   src    = (const int*)d_in[8];
    const int*   dst    = (const int*)d_in[9];
    float* out = (float*)d_out;
    float* ws  = (float*)d_ws;

    int* pred   = (int*)(ws + OFF_PRED);
    int* ssrc   = (int*)(ws + OFF_SSRC);
    int* rowptr = (int*)(ws + OFF_ROWP);
    int* cursor = (int*)(ws + OFF_CURS);
    int* deg_i  = (int*)(ws + OFF_DEGI);
    int* pres   = (int*)(ws + OFF_PRES);
    float* sums = ws + OFF_SUM;

    // zero only the small accumulator block (deg counts, LN sums, present mask)
    hipMemsetAsync(ws + OFF_ZERO, 0, (size_t)(WS_END - OFF_ZERO) * sizeof(float), stream);

    k_pred   <<<(NN + 255) / 256, 256, 0, stream>>>(logits, pred);
    k_count  <<<(EE + 255) / 256, 256, 0, stream>>>(dst, deg_i);
    k_scan   <<<1, 256, 0, stream>>>(deg_i, rowptr, cursor);
    k_scatter<<<(EE + 255) / 256, 256, 0, stream>>>(src, dst, cursor, ssrc);
    k_gemm   <<<NN / 16, 256, 0, stream>>>(hin, Wfc, attn_l, attn_r,
                                           ws + OFF_FEAT, ws + OFF_EL, ws + OFF_ER);
    k_agg    <<<NN / 4, 256, 0, stream>>>(rowptr, ssrc, ws + OFF_EL, ws + OFF_ER,
                                          ws + OFF_FEAT, pred,
                                          ws + OFF_AGG, ws + OFF_F1S, ws + OFF_CNT, pres);
    k_f      <<<(NN * H + 255) / 256, 256, 0, stream>>>(ws + OFF_F1S, ws + OFF_CNT,
                                                        rowptr, pres,
                                                        ws + OFF_F1, ws + OFF_F2, sums);
    k_z      <<<(NN * H + 255) / 256, 256, 0, stream>>>(ws + OFF_F1, ws + OFF_F2,
                                                        sums, old_z, tau1, tau2,
                                                        out + (long)NN * HD, ws + OFF_GATE);
    k_out    <<<(NN * HD + 255) / 256, 256, 0, stream>>>(ws + OFF_FEAT, ws + OFF_AGG,
                                                         ws + OFF_GATE, rowptr, out);
}

// Round 5
// 165.228 us; speedup vs baseline: 8.0304x; 1.3980x over previous
//
#include <hip/hip_runtime.h>
#include <math.h>

constexpr int NN = 10000;
constexpr int EE = 320000;
constexpr int H  = 4;
constexpr int D  = 64;
constexpr int C  = 16;
constexpr int IN = 256;
constexpr int HD = H * D; // 256

// ---- workspace layout (float-element offsets) ----
constexpr long OFF_FEAT = 0;                               // N*HD f32
constexpr long OFF_EL   = OFF_FEAT + (long)NN * HD;        // N*H
constexpr long OFF_ER   = OFF_EL   + (long)NN * H;         // N*H
constexpr long OFF_F1   = OFF_ER   + (long)NN * H;         // N*H
constexpr long OFF_F2   = OFF_F1   + (long)NN * H;         // N*H
constexpr long OFF_AGG  = OFF_F2   + (long)NN * H;         // N*HD
constexpr long OFF_PRED = OFF_AGG  + (long)NN * HD;        // N   (int)
constexpr long OFF_SSRC = OFF_PRED + (long)NN;             // E   (int) src sorted by dst
constexpr long OFF_ROWP = OFF_SSRC + (long)EE;             // N+1 (int)
constexpr long OFF_CURS = OFF_ROWP + (long)NN + 1;         // N   (int)
// zeroed-every-call block:
constexpr long OFF_ZERO = OFF_CURS + (long)NN;
constexpr long OFF_DEGI = OFF_ZERO;                        // N   (int)
constexpr long OFF_SUM  = OFF_DEGI + (long)NN;             // 4 f32 (written by k_sum, no zero needed)
constexpr long WS_END   = OFF_SUM + 4;

constexpr int GB = NN / 16;          // 625 gemm blocks
constexpr int PB = (NN + 255) / 256; // 40 pred blocks
constexpr int CB = (EE + 255) / 256; // 1250 count blocks

// fused front kernel: blocks [0,GB) gemm, [GB,GB+PB) pred, rest count.
// All three parts are mutually independent.
__global__ __launch_bounds__(256) void k_front(const float* __restrict__ hin,
                                               const float* __restrict__ W,
                                               const float* __restrict__ al,
                                               const float* __restrict__ ar,
                                               const float* __restrict__ logits,
                                               const int*   __restrict__ dst,
                                               float* __restrict__ feat,
                                               float* __restrict__ el,
                                               float* __restrict__ er,
                                               int*   __restrict__ pred,
                                               int*   __restrict__ deg_i) {
    __shared__ float hh[16][IN];
    int bid = blockIdx.x;
    int t = threadIdx.x;
    if (bid < GB) {
        // ---- GEMM: feat = h @ Wfc, el/er head-reductions ----
        int n0 = bid * 16;
#pragma unroll
        for (int i = 0; i < 16; ++i) hh[i][t] = hin[(long)(n0 + i) * IN + t];
        __syncthreads();

        float acc[16];
#pragma unroll
        for (int i = 0; i < 16; ++i) acc[i] = 0.f;
        for (int k = 0; k < IN; ++k) {
            float w = W[(long)k * HD + t];
#pragma unroll
            for (int i = 0; i < 16; ++i) acc[i] = fmaf(hh[i][k], w, acc[i]);
        }
#pragma unroll
        for (int i = 0; i < 16; ++i) feat[(long)(n0 + i) * HD + t] = acc[i];

        float aL = al[t], aR = ar[t];
        int hidx = t >> 6;
#pragma unroll
        for (int i = 0; i < 16; ++i) {
            float vl = acc[i] * aL;
            float vr = acc[i] * aR;
            for (int off = 32; off; off >>= 1) {
                vl += __shfl_down(vl, off);
                vr += __shfl_down(vr, off);
            }
            if ((t & 63) == 0) {
                el[(long)(n0 + i) * H + hidx] = vl;
                er[(long)(n0 + i) * H + hidx] = vr;
            }
        }
    } else if (bid < GB + PB) {
        // ---- pred = argmax(logits) ----
        int n = (bid - GB) * 256 + t;
        if (n < NN) {
            const float* row = logits + (long)n * C;
            float best = row[0]; int bi = 0;
#pragma unroll
            for (int c = 1; c < C; ++c) { float v = row[c]; if (v > best) { best = v; bi = c; } }
            pred[n] = bi;
        }
    } else {
        // ---- in-degree counting ----
        int e = (bid - GB - PB) * 256 + t;
        if (e < EE) atomicAdd(&deg_i[dst[e]], 1);
    }
}

// 1024-thread single-block exclusive scan -> rowptr, cursor
__global__ __launch_bounds__(1024) void k_scan(const int* __restrict__ deg_i,
                                               int* __restrict__ rowptr,
                                               int* __restrict__ cursor) {
    __shared__ int lsum[1024];
    constexpr int CH = (NN + 1023) / 1024; // 10
    int t = threadIdx.x;
    int base = t * CH;
    int s = 0;
#pragma unroll
    for (int i = 0; i < CH; ++i) { int idx = base + i; if (idx < NN) s += deg_i[idx]; }
    lsum[t] = s;
    __syncthreads();
    for (int off = 1; off < 1024; off <<= 1) {
        int v = (t >= off) ? lsum[t - off] : 0;
        __syncthreads();
        lsum[t] += v;
        __syncthreads();
    }
    int run = t ? lsum[t - 1] : 0;
#pragma unroll
    for (int i = 0; i < CH; ++i) {
        int idx = base + i;
        if (idx < NN) { rowptr[idx] = run; cursor[idx] = run; run += deg_i[idx]; }
    }
    if (t == 1023) rowptr[NN] = lsum[1023];
}

__global__ __launch_bounds__(256) void k_scatter(const int* __restrict__ src,
                                                 const int* __restrict__ dst,
                                                 int* __restrict__ cursor,
                                                 int* __restrict__ ssrc) {
    int e = blockIdx.x * 256 + threadIdx.x;
    if (e >= EE) return;
    int d = dst[e];
    int pos = atomicAdd(&cursor[d], 1);
    ssrc[pos] = src[e];
}

// one wave per dst node. 16-edge strips; per-edge data broadcast via
// readlane (scalar, uniform feat address) + 1 bpermute for the weight.
// Unrolled 16 -> 16 gathers in flight. f1/f2 computed in-register
// (present-mask dropped: globally-absent classes add a constant to f2
// which cancels exactly in the global LayerNorm).
#define EDGE(kk) { \
    int spk = __builtin_amdgcn_readlane(sp, (kk)); \
    int s_  = spk & 0xFFFF; \
    int ps_ = spk >> 16; \
    float wa = __shfl(w, (hidx << 4) | (kk)); \
    const float4 f = *(const float4*)(feat + (long)s_ * HD + (lane << 2)); \
    acc.x = fmaf(wa, f.x, acc.x); \
    acc.y = fmaf(wa, f.y, acc.y); \
    acc.z = fmaf(wa, f.z, acc.z); \
    acc.w = fmaf(wa, f.w, acc.w); \
    f1a += (ps_ == pd)   ? wa : 0.f; \
    ca  += (ps_ == cidx) ? wa : 0.f; \
}

__global__ __launch_bounds__(256) void k_agg(const int* __restrict__ rowptr,
                                             const int* __restrict__ ssrc,
                                             const float* __restrict__ el,
                                             const float* __restrict__ er,
                                             const float* __restrict__ feat,
                                             const int* __restrict__ pred,
                                             float* __restrict__ agg,
                                             float* __restrict__ f1,
                                             float* __restrict__ f2) {
    int lane = threadIdx.x & 63;
    int n = blockIdx.x * 4 + (threadIdx.x >> 6); // grid = NN/4 exactly
    int beg = rowptr[n], end = rowptr[n + 1];
    int deg = end - beg;
    int hidx = lane >> 4, cidx = lane & 15;
    float Rh = er[(long)n * H + hidx];
    int pd = pred[n];

    float4 acc = {0.f, 0.f, 0.f, 0.f};
    float dsum = 0.f, f1a = 0.f, ca = 0.f;

    for (int base = beg; base < end; base += 16) {
        int nk = end - base; if (nk > 16) nk = 16;
        float w = 0.f; int sp = 0;
        if (cidx < nk) {
            int s = ssrc[base + cidx];
            float x = el[(long)s * H + hidx] + Rh;
            x = x > 0.f ? x : 0.2f * x;
            w = __expf(x);
            if (hidx == 0) sp = s | (pred[s] << 16);
        }
        dsum += w;
        if (nk == 16) {
#pragma unroll
            for (int k = 0; k < 16; ++k) EDGE(k)
        } else {
            for (int k = 0; k < nk; ++k) EDGE(k)
        }
    }

    // per-head softmax denominator: reduce over the 16-lane group
    for (int off = 1; off < 16; off <<= 1) dsum += __shfl_xor(dsum, off);
    float invh = dsum > 0.f ? 1.f / dsum : 0.f;
    float invdeg = 1.0f / (float)(deg > 0 ? deg : 1);

    float4 o;
    o.x = acc.x * invh; o.y = acc.y * invh; o.z = acc.z * invh; o.w = acc.w * invh;
    *(float4*)(agg + (long)n * HD + (lane << 2)) = o;

    // f2 entropy term: lane (h,c) holds its class sum
    float v = fmaxf(ca * invh * invdeg, 1e-5f);
    float term = -v * logf(v);
    for (int off = 1; off < 16; off <<= 1) term += __shfl_xor(term, off);
    if (cidx == 0) {
        f1[(long)n * H + hidx] = f1a * invh * invdeg;
        f2[(long)n * H + hidx] = term;
    }
}

// single-block reduction of f1/f2 -> sums[4] (plain stores, no atomics)
__global__ __launch_bounds__(1024) void k_sum(const float* __restrict__ f1,
                                              const float* __restrict__ f2,
                                              float* __restrict__ sums) {
    __shared__ float red[16][4];
    float s1 = 0.f, q1 = 0.f, s2 = 0.f, q2 = 0.f;
    for (int i = threadIdx.x; i < NN * H; i += 1024) {
        float a = f1[i], b = f2[i];
        s1 += a; q1 = fmaf(a, a, q1);
        s2 += b; q2 = fmaf(b, b, q2);
    }
    for (int off = 32; off; off >>= 1) {
        s1 += __shfl_down(s1, off);
        q1 += __shfl_down(q1, off);
        s2 += __shfl_down(s2, off);
        q2 += __shfl_down(q2, off);
    }
    int wid = threadIdx.x >> 6;
    if ((threadIdx.x & 63) == 0) {
        red[wid][0] = s1; red[wid][1] = q1; red[wid][2] = s2; red[wid][3] = q2;
    }
    __syncthreads();
    if (threadIdx.x < 4) {
        float a = 0.f;
        for (int wv = 0; wv < 16; ++wv) a += red[wv][threadIdx.x];
        sums[threadIdx.x] = a;
    }
}

// fused: z/gate (LayerNorm'd f1,f2) + final output
__global__ __launch_bounds__(256) void k_out(const float* __restrict__ feat,
                                             const float* __restrict__ agg,
                                             const float* __restrict__ f1,
                                             const float* __restrict__ f2,
                                             const float* __restrict__ sums,
                                             const float* __restrict__ old_z,
                                             const float* __restrict__ tau1,
                                             const float* __restrict__ tau2,
                                             const int* __restrict__ rowptr,
                                             float* __restrict__ out,
                                             float* __restrict__ zout) {
    long i = (long)blockIdx.x * 256 + threadIdx.x;
    if (i >= (long)NN * HD) return;
    int n = (int)(i >> 8);
    int h = (int)((i >> 6) & 3);
    int t = n * H + h;
    constexpr float invNH = 1.0f / (NN * H);
    float mu1 = sums[0] * invNH, mu2 = sums[2] * invNH;
    float v1 = fmaxf(sums[1] * invNH - mu1 * mu1, 0.f);
    float v2 = fmaxf(sums[3] * invNH - mu2 * mu2, 0.f);
    float r1 = rsqrtf(v1 + 1e-5f), r2 = rsqrtf(v2 + 1e-5f);
    float nf1 = (f1[t] - mu1) * r1;
    float nf2 = (f2[t] - mu2) * r2;
    float z = (1.f / (1.f + expf(nf1 - tau1[0]))) * (1.f / (1.f + expf(nf2 - tau2[0])));
    float gate = fminf(old_z[t], z);
    if ((i & 63) == 0) zout[t] = z;
    int deg = rowptr[n + 1] - rowptr[n];
    float nrm = rsqrtf((float)(deg > 0 ? deg : 1));
    out[i] = feat[i] + gate * agg[i] * nrm;
}

extern "C" void kernel_launch(void* const* d_in, const int* in_sizes, int n_in,
                              void* d_out, int out_size, void* d_ws, size_t ws_size,
                              hipStream_t stream) {
    const float* hin    = (const float*)d_in[0];
    const float* logits = (const float*)d_in[1];
    const float* old_z  = (const float*)d_in[2];
    const float* attn_l = (const float*)d_in[3];
    const float* attn_r = (const float*)d_in[4];
    const float* Wfc    = (const float*)d_in[5];
    const float* tau1   = (const float*)d_in[6];
    const float* tau2   = (const float*)d_in[7];
    const int*   src    = (const int*)d_in[8];
    const int*   dst    = (const int*)d_in[9];
    float* out = (float*)d_out;
    float* ws  = (float*)d_ws;

    int* pred   = (int*)(ws + OFF_PRED);
    int* ssrc   = (int*)(ws + OFF_SSRC);
    int* rowptr = (int*)(ws + OFF_ROWP);
    int* cursor = (int*)(ws + OFF_CURS);
    int* deg_i  = (int*)(ws + OFF_DEGI);
    float* sums = ws + OFF_SUM;

    // zero only the degree counters (sums are plain-stored by k_sum)
    hipMemsetAsync(deg_i, 0, (size_t)NN * sizeof(int), stream);

    k_front  <<<GB + PB + CB, 256, 0, stream>>>(hin, Wfc, attn_l, attn_r, logits, dst,
                                                ws + OFF_FEAT, ws + OFF_EL, ws + OFF_ER,
                                                pred, deg_i);
    k_scan   <<<1, 1024, 0, stream>>>(deg_i, rowptr, cursor);
    k_scatter<<<(EE + 255) / 256, 256, 0, stream>>>(src, dst, cursor, ssrc);
    k_agg    <<<NN / 4, 256, 0, stream>>>(rowptr, ssrc, ws + OFF_EL, ws + OFF_ER,
                                          ws + OFF_FEAT, pred,
                                          ws + OFF_AGG, ws + OFF_F1, ws + OFF_F2);
    k_sum    <<<1, 1024, 0, stream>>>(ws + OFF_F1, ws + OFF_F2, sums);
    k_out    <<<(NN * HD + 255) / 256, 256, 0, stream>>>(ws + OFF_FEAT, ws + OFF_AGG,
                                                         ws + OFF_F1, ws + OFF_F2, sums,
                                                         old_z, tau1, tau2, rowptr,
                                                         out, out + (long)NN * HD);
}

// Round 6
// 149.186 us; speedup vs baseline: 8.8940x; 1.1075x over previous
//
#include <hip/hip_runtime.h>
#include <math.h>

constexpr int NN = 10000;
constexpr int EE = 320000;
constexpr int H  = 4;
constexpr int D  = 64;
constexpr int C  = 16;
constexpr int IN = 256;
constexpr int HD = H * D; // 256

// ---- workspace layout (float-element offsets) ----
constexpr long OFF_FEAT = 0;                               // N*HD f32
constexpr long OFF_FB   = OFF_FEAT + (long)NN * HD;        // N*HD bf16 = N*HD/2 floats
constexpr long OFF_EL   = OFF_FB   + (long)NN * HD / 2;    // N*H
constexpr long OFF_ER   = OFF_EL   + (long)NN * H;         // N*H
constexpr long OFF_F1   = OFF_ER   + (long)NN * H;         // N*H
constexpr long OFF_F2   = OFF_F1   + (long)NN * H;         // N*H
constexpr long OFF_AGG  = OFF_F2   + (long)NN * H;         // N*HD
constexpr long OFF_PRED = OFF_AGG  + (long)NN * HD;        // N   (int)
constexpr long OFF_SSRC = OFF_PRED + (long)NN;             // E   (int) src sorted by dst
constexpr long OFF_ROWP = OFF_SSRC + (long)EE;             // N+1 (int)
constexpr long OFF_CURS = OFF_ROWP + (long)NN + 1;         // N   (int)
constexpr long OFF_DEGI = OFF_CURS + (long)NN;             // N   (int, zeroed per call)
constexpr long OFF_SUM  = OFF_DEGI + (long)NN;             // 4 f32 (plain-stored by k_sum)
constexpr long WS_END   = OFF_SUM + 4;

constexpr int GB = NN / 8;           // 1250 gemm blocks (8 nodes each)
constexpr int PB = (NN + 255) / 256; // 40 pred blocks
constexpr int CB = (EE + 255) / 256; // 1250 count blocks

// fused front kernel: blocks [0,GB) gemm, [GB,GB+PB) pred, rest in-degree count.
// GEMM: no LDS. h-loads are wave-uniform -> scalar s_load_dwordx4; each wave
// owns 64 output cols (= one head) x 8 nodes; W loads coalesced 256B/wave,
// no intra-block duplication. Also emits RNE bf16 copy of feat for k_agg.
__global__ __launch_bounds__(256) void k_front(const float* __restrict__ hin,
                                               const float* __restrict__ W,
                                               const float* __restrict__ al,
                                               const float* __restrict__ ar,
                                               const float* __restrict__ logits,
                                               const int*   __restrict__ dst,
                                               float* __restrict__ feat,
                                               unsigned short* __restrict__ featb,
                                               float* __restrict__ el,
                                               float* __restrict__ er,
                                               int*   __restrict__ pred,
                                               int*   __restrict__ deg_i) {
    int bid = blockIdx.x;
    int t = threadIdx.x;
    if (bid < GB) {
        // ---- GEMM: feat = h @ Wfc, el/er head-reductions ----
        int n0 = bid * 8;
        int w = t >> 6;        // wave = head (cols w*64..w*64+63), col == t
        int lane = t & 63;
        float acc[8];
#pragma unroll
        for (int i = 0; i < 8; ++i) acc[i] = 0.f;

        for (int k = 0; k < IN; k += 4) {
            float wr[4];
#pragma unroll
            for (int j = 0; j < 4; ++j) wr[j] = W[(long)(k + j) * HD + t];
#pragma unroll
            for (int i = 0; i < 8; ++i) {
                const float4 hv = *(const float4*)(hin + (long)(n0 + i) * IN + k);
                acc[i] = fmaf(hv.x, wr[0], acc[i]);
                acc[i] = fmaf(hv.y, wr[1], acc[i]);
                acc[i] = fmaf(hv.z, wr[2], acc[i]);
                acc[i] = fmaf(hv.w, wr[3], acc[i]);
            }
        }

        float aL = al[t], aR = ar[t];
#pragma unroll
        for (int i = 0; i < 8; ++i) {
            feat[(long)(n0 + i) * HD + t] = acc[i];
            unsigned int b = __float_as_uint(acc[i]);
            featb[(long)(n0 + i) * HD + t] =
                (unsigned short)((b + 0x7FFFu + ((b >> 16) & 1u)) >> 16); // RNE bf16
            float vl = acc[i] * aL;
            float vr = acc[i] * aR;
            for (int off = 32; off; off >>= 1) {
                vl += __shfl_down(vl, off);
                vr += __shfl_down(vr, off);
            }
            if (lane == 0) {
                el[(long)(n0 + i) * H + w] = vl;
                er[(long)(n0 + i) * H + w] = vr;
            }
        }
    } else if (bid < GB + PB) {
        // ---- pred = argmax(logits) ----
        int n = (bid - GB) * 256 + t;
        if (n < NN) {
            const float* row = logits + (long)n * C;
            float best = row[0]; int bi = 0;
#pragma unroll
            for (int c = 1; c < C; ++c) { float v = row[c]; if (v > best) { best = v; bi = c; } }
            pred[n] = bi;
        }
    } else {
        // ---- in-degree counting ----
        int e = (bid - GB - PB) * 256 + t;
        if (e < EE) atomicAdd(&deg_i[dst[e]], 1);
    }
}

// 1024-thread single-block exclusive scan -> rowptr, cursor
__global__ __launch_bounds__(1024) void k_scan(const int* __restrict__ deg_i,
                                               int* __restrict__ rowptr,
                                               int* __restrict__ cursor) {
    __shared__ int lsum[1024];
    constexpr int CH = (NN + 1023) / 1024; // 10
    int t = threadIdx.x;
    int base = t * CH;
    int s = 0;
#pragma unroll
    for (int i = 0; i < CH; ++i) { int idx = base + i; if (idx < NN) s += deg_i[idx]; }
    lsum[t] = s;
    __syncthreads();
    for (int off = 1; off < 1024; off <<= 1) {
        int v = (t >= off) ? lsum[t - off] : 0;
        __syncthreads();
        lsum[t] += v;
        __syncthreads();
    }
    int run = t ? lsum[t - 1] : 0;
#pragma unroll
    for (int i = 0; i < CH; ++i) {
        int idx = base + i;
        if (idx < NN) { rowptr[idx] = run; cursor[idx] = run; run += deg_i[idx]; }
    }
    if (t == 1023) rowptr[NN] = lsum[1023];
}

__global__ __launch_bounds__(256) void k_scatter(const int* __restrict__ src,
                                                 const int* __restrict__ dst,
                                                 int* __restrict__ cursor,
                                                 int* __restrict__ ssrc) {
    int e = blockIdx.x * 256 + threadIdx.x;
    if (e >= EE) return;
    int d = dst[e];
    int pos = atomicAdd(&cursor[d], 1);
    ssrc[pos] = src[e];
}

// one wave per dst node. 16-edge strips; per-edge (src,pred) broadcast via
// readlane (scalar-uniform gather address) + 1 shfl for the weight.
// feat gathered in bf16 (512B/row) to halve L2-miss traffic.
#define EDGE(kk) { \
    int spk = __builtin_amdgcn_readlane(sp, (kk)); \
    int s_  = spk & 0xFFFF; \
    int ps_ = spk >> 16; \
    float wa = __shfl(w, (hidx << 4) | (kk)); \
    const ushort4 f = *(const ushort4*)(featb + (long)s_ * HD + (lane << 2)); \
    acc.x = fmaf(wa, __uint_as_float((unsigned int)f.x << 16), acc.x); \
    acc.y = fmaf(wa, __uint_as_float((unsigned int)f.y << 16), acc.y); \
    acc.z = fmaf(wa, __uint_as_float((unsigned int)f.z << 16), acc.z); \
    acc.w = fmaf(wa, __uint_as_float((unsigned int)f.w << 16), acc.w); \
    f1a += (ps_ == pd)   ? wa : 0.f; \
    ca  += (ps_ == cidx) ? wa : 0.f; \
}

__global__ __launch_bounds__(256) void k_agg(const int* __restrict__ rowptr,
                                             const int* __restrict__ ssrc,
                                             const float* __restrict__ el,
                                             const float* __restrict__ er,
                                             const unsigned short* __restrict__ featb,
                                             const int* __restrict__ pred,
                                             float* __restrict__ agg,
                                             float* __restrict__ f1,
                                             float* __restrict__ f2) {
    int lane = threadIdx.x & 63;
    int n = blockIdx.x * 4 + (threadIdx.x >> 6); // grid = NN/4 exactly
    int beg = rowptr[n], end = rowptr[n + 1];
    int deg = end - beg;
    int hidx = lane >> 4, cidx = lane & 15;
    float Rh = er[(long)n * H + hidx];
    int pd = pred[n];

    float4 acc = {0.f, 0.f, 0.f, 0.f};
    float dsum = 0.f, f1a = 0.f, ca = 0.f;

    for (int base = beg; base < end; base += 16) {
        int nk = end - base; if (nk > 16) nk = 16;
        float w = 0.f; int sp = 0;
        if (cidx < nk) {
            int s = ssrc[base + cidx];
            float x = el[(long)s * H + hidx] + Rh;
            x = x > 0.f ? x : 0.2f * x;
            w = __expf(x);
            if (hidx == 0) sp = s | (pred[s] << 16);
        }
        dsum += w;
        if (nk == 16) {
#pragma unroll
            for (int k = 0; k < 16; ++k) EDGE(k)
        } else {
            for (int k = 0; k < nk; ++k) EDGE(k)
        }
    }

    // per-head softmax denominator: reduce over the 16-lane group
    for (int off = 1; off < 16; off <<= 1) dsum += __shfl_xor(dsum, off);
    float invh = dsum > 0.f ? 1.f / dsum : 0.f;
    float invdeg = 1.0f / (float)(deg > 0 ? deg : 1);

    float4 o;
    o.x = acc.x * invh; o.y = acc.y * invh; o.z = acc.z * invh; o.w = acc.w * invh;
    *(float4*)(agg + (long)n * HD + (lane << 2)) = o;

    // f2 entropy term: lane (h,c) holds its class sum. (Globally-absent
    // classes contribute a constant that cancels in the global LayerNorm.)
    float v = fmaxf(ca * invh * invdeg, 1e-5f);
    float term = -v * logf(v);
    for (int off = 1; off < 16; off <<= 1) term += __shfl_xor(term, off);
    if (cidx == 0) {
        f1[(long)n * H + hidx] = f1a * invh * invdeg;
        f2[(long)n * H + hidx] = term;
    }
}

// single-block reduction of f1/f2 -> sums[4] (plain stores, deterministic)
__global__ __launch_bounds__(1024) void k_sum(const float* __restrict__ f1,
                                              const float* __restrict__ f2,
                                              float* __restrict__ sums) {
    __shared__ float red[16][4];
    float s1 = 0.f, q1 = 0.f, s2 = 0.f, q2 = 0.f;
    for (int i = threadIdx.x; i < NN * H; i += 1024) {
        float a = f1[i], b = f2[i];
        s1 += a; q1 = fmaf(a, a, q1);
        s2 += b; q2 = fmaf(b, b, q2);
    }
    for (int off = 32; off; off >>= 1) {
        s1 += __shfl_down(s1, off);
        q1 += __shfl_down(q1, off);
        s2 += __shfl_down(s2, off);
        q2 += __shfl_down(q2, off);
    }
    int wid = threadIdx.x >> 6;
    if ((threadIdx.x & 63) == 0) {
        red[wid][0] = s1; red[wid][1] = q1; red[wid][2] = s2; red[wid][3] = q2;
    }
    __syncthreads();
    if (threadIdx.x < 4) {
        float a = 0.f;
        for (int wv = 0; wv < 16; ++wv) a += red[wv][threadIdx.x];
        sums[threadIdx.x] = a;
    }
}

// fused: z/gate (LayerNorm'd f1,f2) + final output
__global__ __launch_bounds__(256) void k_out(const float* __restrict__ feat,
                                             const float* __restrict__ agg,
                                             const float* __restrict__ f1,
                                             const float* __restrict__ f2,
                                             const float* __restrict__ sums,
                                             const float* __restrict__ old_z,
                                             const float* __restrict__ tau1,
                                             const float* __restrict__ tau2,
                                             const int* __restrict__ rowptr,
                                             float* __restrict__ out,
                                             float* __restrict__ zout) {
    long i = (long)blockIdx.x * 256 + threadIdx.x;
    if (i >= (long)NN * HD) return;
    int n = (int)(i >> 8);
    int h = (int)((i >> 6) & 3);
    int t = n * H + h;
    constexpr float invNH = 1.0f / (NN * H);
    float mu1 = sums[0] * invNH, mu2 = sums[2] * invNH;
    float v1 = fmaxf(sums[1] * invNH - mu1 * mu1, 0.f);
    float v2 = fmaxf(sums[3] * invNH - mu2 * mu2, 0.f);
    float r1 = rsqrtf(v1 + 1e-5f), r2 = rsqrtf(v2 + 1e-5f);
    float nf1 = (f1[t] - mu1) * r1;
    float nf2 = (f2[t] - mu2) * r2;
    float z = (1.f / (1.f + expf(nf1 - tau1[0]))) * (1.f / (1.f + expf(nf2 - tau2[0])));
    float gate = fminf(old_z[t], z);
    if ((i & 63) == 0) zout[t] = z;
    int deg = rowptr[n + 1] - rowptr[n];
    float nrm = rsqrtf((float)(deg > 0 ? deg : 1));
    out[i] = feat[i] + gate * agg[i] * nrm;
}

extern "C" void kernel_launch(void* const* d_in, const int* in_sizes, int n_in,
                              void* d_out, int out_size, void* d_ws, size_t ws_size,
                              hipStream_t stream) {
    const float* hin    = (const float*)d_in[0];
    const float* logits = (const float*)d_in[1];
    const float* old_z  = (const float*)d_in[2];
    const float* attn_l = (const float*)d_in[3];
    const float* attn_r = (const float*)d_in[4];
    const float* Wfc    = (const float*)d_in[5];
    const float* tau1   = (const float*)d_in[6];
    const float* tau2   = (const float*)d_in[7];
    const int*   src    = (const int*)d_in[8];
    const int*   dst    = (const int*)d_in[9];
    float* out = (float*)d_out;
    float* ws  = (float*)d_ws;

    unsigned short* featb = (unsigned short*)(ws + OFF_FB);
    int* pred   = (int*)(ws + OFF_PRED);
    int* ssrc   = (int*)(ws + OFF_SSRC);
    int* rowptr = (int*)(ws + OFF_ROWP);
    int* cursor = (int*)(ws + OFF_CURS);
    int* deg_i  = (int*)(ws + OFF_DEGI);
    float* sums = ws + OFF_SUM;

    // zero only the degree counters
    hipMemsetAsync(deg_i, 0, (size_t)NN * sizeof(int), stream);

    k_front  <<<GB + PB + CB, 256, 0, stream>>>(hin, Wfc, attn_l, attn_r, logits, dst,
                                                ws + OFF_FEAT, featb,
                                                ws + OFF_EL, ws + OFF_ER,
                                                pred, deg_i);
    k_scan   <<<1, 1024, 0, stream>>>(deg_i, rowptr, cursor);
    k_scatter<<<(EE + 255) / 256, 256, 0, stream>>>(src, dst, cursor, ssrc);
    k_agg    <<<NN / 4, 256, 0, stream>>>(rowptr, ssrc, ws + OFF_EL, ws + OFF_ER,
                                          featb, pred,
                                          ws + OFF_AGG, ws + OFF_F1, ws + OFF_F2);
    k_sum    <<<1, 1024, 0, stream>>>(ws + OFF_F1, ws + OFF_F2, sums);
    k_out    <<<(NN * HD + 255) / 256, 256, 0, stream>>>(ws + OFF_FEAT, ws + OFF_AGG,
                                                         ws + OFF_F1, ws + OFF_F2, sums,
                                                         old_z, tau1, tau2, rowptr,
                                                         out, out + (long)NN * HD);
}

// Round 7
// 141.298 us; speedup vs baseline: 9.3905x; 1.0558x over previous
//
#include <hip/hip_runtime.h>
#include <math.h>

constexpr int NN = 10000;
constexpr int EE = 320000;
constexpr int H  = 4;
constexpr int D  = 64;
constexpr int C  = 16;
constexpr int IN = 256;
constexpr int HD = H * D; // 256

// ---- workspace layout (float-element offsets) ----
constexpr long OFF_FEAT = 0;                               // N*HD f32
constexpr long OFF_FB   = OFF_FEAT + (long)NN * HD;        // N*HD bf16 = N*HD/2 floats
constexpr long OFF_EL   = OFF_FB   + (long)NN * HD / 2;    // N*H
constexpr long OFF_ER   = OFF_EL   + (long)NN * H;         // N*H
constexpr long OFF_F1   = OFF_ER   + (long)NN * H;         // N*H
constexpr long OFF_F2   = OFF_F1   + (long)NN * H;         // N*H
constexpr long OFF_AGG  = OFF_F2   + (long)NN * H;         // N*HD
constexpr long OFF_PRED = OFF_AGG  + (long)NN * HD;        // N   (int)
constexpr long OFF_SSRC = OFF_PRED + (long)NN;             // E   (int) src sorted by dst
constexpr long OFF_ROWP = OFF_SSRC + (long)EE;             // N+1 (int)
constexpr long OFF_CURS = OFF_ROWP + (long)NN + 1;         // N   (int)
constexpr long OFF_DEGI = OFF_CURS + (long)NN;             // N   (int, zeroed per call)
constexpr long OFF_SUM  = OFF_DEGI + (long)NN;             // 4 f32 (plain-stored by k_sum)
constexpr long WS_END   = OFF_SUM + 4;

constexpr int GB = NN / 8;           // 1250 gemm blocks (8 nodes each)
constexpr int PB = (NN + 255) / 256; // 40 pred blocks
constexpr int CB = (EE + 255) / 256; // 1250 count blocks

// fused front kernel: blocks [0,GB) gemm, [GB,GB+PB) pred, rest in-degree count.
// GEMM: h loaded via coalesced VECTOR loads into VGPRs (lane = k within a
// 64-wide chunk), broadcast per-k with v_readlane (register-resident, no
// scalar-cache traffic). W: one coalesced 256B/wave load per k, all
// independent -> deep memory-level parallelism. Each wave owns one head
// (64 cols) x 8 nodes. Also emits RNE bf16 copy of feat for k_agg.
__global__ __launch_bounds__(256) void k_front(const float* __restrict__ hin,
                                               const float* __restrict__ W,
                                               const float* __restrict__ al,
                                               const float* __restrict__ ar,
                                               const float* __restrict__ logits,
                                               const int*   __restrict__ dst,
                                               float* __restrict__ feat,
                                               unsigned short* __restrict__ featb,
                                               float* __restrict__ el,
                                               float* __restrict__ er,
                                               int*   __restrict__ pred,
                                               int*   __restrict__ deg_i) {
    int bid = blockIdx.x;
    int t = threadIdx.x;
    if (bid < GB) {
        // ---- GEMM: feat = h @ Wfc, el/er head-reductions ----
        int n0 = bid * 8;
        int w = t >> 6;        // wave = head; col == t
        int lane = t & 63;
        float acc[8];
#pragma unroll
        for (int i = 0; i < 8; ++i) acc[i] = 0.f;

        for (int kc = 0; kc < IN; kc += 64) {
            // h chunk into VGPRs: lane holds h[n0+i][kc+lane]
            float hreg[8];
#pragma unroll
            for (int i = 0; i < 8; ++i)
                hreg[i] = hin[(long)(n0 + i) * IN + kc + lane];
#pragma unroll
            for (int kk = 0; kk < 64; ++kk) {
                float wv = W[(long)(kc + kk) * HD + t];
#pragma unroll
                for (int i = 0; i < 8; ++i) {
                    float hb = __uint_as_float(
                        __builtin_amdgcn_readlane(__float_as_uint(hreg[i]), kk));
                    acc[i] = fmaf(hb, wv, acc[i]);
                }
            }
        }

        float aL = al[t], aR = ar[t];
#pragma unroll
        for (int i = 0; i < 8; ++i) {
            feat[(long)(n0 + i) * HD + t] = acc[i];
            unsigned int b = __float_as_uint(acc[i]);
            featb[(long)(n0 + i) * HD + t] =
                (unsigned short)((b + 0x7FFFu + ((b >> 16) & 1u)) >> 16); // RNE bf16
            float vl = acc[i] * aL;
            float vr = acc[i] * aR;
            for (int off = 32; off; off >>= 1) {
                vl += __shfl_down(vl, off);
                vr += __shfl_down(vr, off);
            }
            if (lane == 0) {
                el[(long)(n0 + i) * H + w] = vl;
                er[(long)(n0 + i) * H + w] = vr;
            }
        }
    } else if (bid < GB + PB) {
        // ---- pred = argmax(logits) ----
        int n = (bid - GB) * 256 + t;
        if (n < NN) {
            const float* row = logits + (long)n * C;
            float best = row[0]; int bi = 0;
#pragma unroll
            for (int c = 1; c < C; ++c) { float v = row[c]; if (v > best) { best = v; bi = c; } }
            pred[n] = bi;
        }
    } else {
        // ---- in-degree counting ----
        int e = (bid - GB - PB) * 256 + t;
        if (e < EE) atomicAdd(&deg_i[dst[e]], 1);
    }
}

// 1024-thread single-block exclusive scan -> rowptr, cursor
__global__ __launch_bounds__(1024) void k_scan(const int* __restrict__ deg_i,
                                               int* __restrict__ rowptr,
                                               int* __restrict__ cursor) {
    __shared__ int lsum[1024];
    constexpr int CH = (NN + 1023) / 1024; // 10
    int t = threadIdx.x;
    int base = t * CH;
    int s = 0;
#pragma unroll
    for (int i = 0; i < CH; ++i) { int idx = base + i; if (idx < NN) s += deg_i[idx]; }
    lsum[t] = s;
    __syncthreads();
    for (int off = 1; off < 1024; off <<= 1) {
        int v = (t >= off) ? lsum[t - off] : 0;
        __syncthreads();
        lsum[t] += v;
        __syncthreads();
    }
    int run = t ? lsum[t - 1] : 0;
#pragma unroll
    for (int i = 0; i < CH; ++i) {
        int idx = base + i;
        if (idx < NN) { rowptr[idx] = run; cursor[idx] = run; run += deg_i[idx]; }
    }
    if (t == 1023) rowptr[NN] = lsum[1023];
}

__global__ __launch_bounds__(256) void k_scatter(const int* __restrict__ src,
                                                 const int* __restrict__ dst,
                                                 int* __restrict__ cursor,
                                                 int* __restrict__ ssrc) {
    int e = blockIdx.x * 256 + threadIdx.x;
    if (e >= EE) return;
    int d = dst[e];
    int pos = atomicAdd(&cursor[d], 1);
    ssrc[pos] = src[e];
}

// one wave per dst node. 16-edge strips; per-edge (src,pred) broadcast via
// readlane (scalar-uniform gather address) + 1 shfl for the weight.
// feat gathered in bf16 (512B/row) to halve L2-miss traffic.
#define EDGE(kk) { \
    int spk = __builtin_amdgcn_readlane(sp, (kk)); \
    int s_  = spk & 0xFFFF; \
    int ps_ = spk >> 16; \
    float wa = __shfl(w, (hidx << 4) | (kk)); \
    const ushort4 f = *(const ushort4*)(featb + (long)s_ * HD + (lane << 2)); \
    acc.x = fmaf(wa, __uint_as_float((unsigned int)f.x << 16), acc.x); \
    acc.y = fmaf(wa, __uint_as_float((unsigned int)f.y << 16), acc.y); \
    acc.z = fmaf(wa, __uint_as_float((unsigned int)f.z << 16), acc.z); \
    acc.w = fmaf(wa, __uint_as_float((unsigned int)f.w << 16), acc.w); \
    f1a += (ps_ == pd)   ? wa : 0.f; \
    ca  += (ps_ == cidx) ? wa : 0.f; \
}

__global__ __launch_bounds__(256) void k_agg(const int* __restrict__ rowptr,
                                             const int* __restrict__ ssrc,
                                             const float* __restrict__ el,
                                             const float* __restrict__ er,
                                             const unsigned short* __restrict__ featb,
                                             const int* __restrict__ pred,
                                             float* __restrict__ agg,
                                             float* __restrict__ f1,
                                             float* __restrict__ f2) {
    int lane = threadIdx.x & 63;
    int n = blockIdx.x * 4 + (threadIdx.x >> 6); // grid = NN/4 exactly
    int beg = rowptr[n], end = rowptr[n + 1];
    int deg = end - beg;
    int hidx = lane >> 4, cidx = lane & 15;
    float Rh = er[(long)n * H + hidx];
    int pd = pred[n];

    float4 acc = {0.f, 0.f, 0.f, 0.f};
    float dsum = 0.f, f1a = 0.f, ca = 0.f;

    for (int base = beg; base < end; base += 16) {
        int nk = end - base; if (nk > 16) nk = 16;
        float w = 0.f; int sp = 0;
        if (cidx < nk) {
            int s = ssrc[base + cidx];
            float x = el[(long)s * H + hidx] + Rh;
            x = x > 0.f ? x : 0.2f * x;
            w = __expf(x);
            if (hidx == 0) sp = s | (pred[s] << 16);
        }
        dsum += w;
        if (nk == 16) {
#pragma unroll
            for (int k = 0; k < 16; ++k) EDGE(k)
        } else {
            for (int k = 0; k < nk; ++k) EDGE(k)
        }
    }

    // per-head softmax denominator: reduce over the 16-lane group
    for (int off = 1; off < 16; off <<= 1) dsum += __shfl_xor(dsum, off);
    float invh = dsum > 0.f ? 1.f / dsum : 0.f;
    float invdeg = 1.0f / (float)(deg > 0 ? deg : 1);

    float4 o;
    o.x = acc.x * invh; o.y = acc.y * invh; o.z = acc.z * invh; o.w = acc.w * invh;
    *(float4*)(agg + (long)n * HD + (lane << 2)) = o;

    // f2 entropy term: lane (h,c) holds its class sum. (Globally-absent
    // classes contribute a constant that cancels in the global LayerNorm.)
    float v = fmaxf(ca * invh * invdeg, 1e-5f);
    float term = -v * logf(v);
    for (int off = 1; off < 16; off <<= 1) term += __shfl_xor(term, off);
    if (cidx == 0) {
        f1[(long)n * H + hidx] = f1a * invh * invdeg;
        f2[(long)n * H + hidx] = term;
    }
}

// single-block reduction of f1/f2 -> sums[4] (plain stores, deterministic)
__global__ __launch_bounds__(1024) void k_sum(const float* __restrict__ f1,
                                              const float* __restrict__ f2,
                                              float* __restrict__ sums) {
    __shared__ float red[16][4];
    float s1 = 0.f, q1 = 0.f, s2 = 0.f, q2 = 0.f;
    for (int i = threadIdx.x; i < NN * H; i += 1024) {
        float a = f1[i], b = f2[i];
        s1 += a; q1 = fmaf(a, a, q1);
        s2 += b; q2 = fmaf(b, b, q2);
    }
    for (int off = 32; off; off >>= 1) {
        s1 += __shfl_down(s1, off);
        q1 += __shfl_down(q1, off);
        s2 += __shfl_down(s2, off);
        q2 += __shfl_down(q2, off);
    }
    int wid = threadIdx.x >> 6;
    if ((threadIdx.x & 63) == 0) {
        red[wid][0] = s1; red[wid][1] = q1; red[wid][2] = s2; red[wid][3] = q2;
    }
    __syncthreads();
    if (threadIdx.x < 4) {
        float a = 0.f;
        for (int wv = 0; wv < 16; ++wv) a += red[wv][threadIdx.x];
        sums[threadIdx.x] = a;
    }
}

// fused: z/gate (LayerNorm'd f1,f2) + final output
__global__ __launch_bounds__(256) void k_out(const float* __restrict__ feat,
                                             const float* __restrict__ agg,
                                             const float* __restrict__ f1,
                                             const float* __restrict__ f2,
                                             const float* __restrict__ sums,
                                             const float* __restrict__ old_z,
                                             const float* __restrict__ tau1,
                                             const float* __restrict__ tau2,
                                             const int* __restrict__ rowptr,
                                             float* __restrict__ out,
                                             float* __restrict__ zout) {
    long i = (long)blockIdx.x * 256 + threadIdx.x;
    if (i >= (long)NN * HD) return;
    int n = (int)(i >> 8);
    int h = (int)((i >> 6) & 3);
    int t = n * H + h;
    constexpr float invNH = 1.0f / (NN * H);
    float mu1 = sums[0] * invNH, mu2 = sums[2] * invNH;
    float v1 = fmaxf(sums[1] * invNH - mu1 * mu1, 0.f);
    float v2 = fmaxf(sums[3] * invNH - mu2 * mu2, 0.f);
    float r1 = rsqrtf(v1 + 1e-5f), r2 = rsqrtf(v2 + 1e-5f);
    float nf1 = (f1[t] - mu1) * r1;
    float nf2 = (f2[t] - mu2) * r2;
    float z = (1.f / (1.f + expf(nf1 - tau1[0]))) * (1.f / (1.f + expf(nf2 - tau2[0])));
    float gate = fminf(old_z[t], z);
    if ((i & 63) == 0) zout[t] = z;
    int deg = rowptr[n + 1] - rowptr[n];
    float nrm = rsqrtf((float)(deg > 0 ? deg : 1));
    out[i] = feat[i] + gate * agg[i] * nrm;
}

extern "C" void kernel_launch(void* const* d_in, const int* in_sizes, int n_in,
                              void* d_out, int out_size, void* d_ws, size_t ws_size,
                              hipStream_t stream) {
    const float* hin    = (const float*)d_in[0];
    const float* logits = (const float*)d_in[1];
    const float* old_z  = (const float*)d_in[2];
    const float* attn_l = (const float*)d_in[3];
    const float* attn_r = (const float*)d_in[4];
    const float* Wfc    = (const float*)d_in[5];
    const float* tau1   = (const float*)d_in[6];
    const float* tau2   = (const float*)d_in[7];
    const int*   src    = (const int*)d_in[8];
    const int*   dst    = (const int*)d_in[9];
    float* out = (float*)d_out;
    float* ws  = (float*)d_ws;

    unsigned short* featb = (unsigned short*)(ws + OFF_FB);
    int* pred   = (int*)(ws + OFF_PRED);
    int* ssrc   = (int*)(ws + OFF_SSRC);
    int* rowptr = (int*)(ws + OFF_ROWP);
    int* cursor = (int*)(ws + OFF_CURS);
    int* deg_i  = (int*)(ws + OFF_DEGI);
    float* sums = ws + OFF_SUM;

    // zero only the degree counters
    hipMemsetAsync(deg_i, 0, (size_t)NN * sizeof(int), stream);

    k_front  <<<GB + PB + CB, 256, 0, stream>>>(hin, Wfc, attn_l, attn_r, logits, dst,
                                                ws + OFF_FEAT, featb,
                                                ws + OFF_EL, ws + OFF_ER,
                                                pred, deg_i);
    k_scan   <<<1, 1024, 0, stream>>>(deg_i, rowptr, cursor);
    k_scatter<<<(EE + 255) / 256, 256, 0, stream>>>(src, dst, cursor, ssrc);
    k_agg    <<<NN / 4, 256, 0, stream>>>(rowptr, ssrc, ws + OFF_EL, ws + OFF_ER,
                                          featb, pred,
                                          ws + OFF_AGG, ws + OFF_F1, ws + OFF_F2);
    k_sum    <<<1, 1024, 0, stream>>>(ws + OFF_F1, ws + OFF_F2, sums);
    k_out    <<<(NN * HD + 255) / 256, 256, 0, stream>>>(ws + OFF_FEAT, ws + OFF_AGG,
                                                         ws + OFF_F1, ws + OFF_F2, sums,
                                                         old_z, tau1, tau2, rowptr,
                                                         out, out + (long)NN * HD);
}

// Round 8
// 129.083 us; speedup vs baseline: 10.2791x; 1.0946x over previous
//
#include <hip/hip_runtime.h>
#include <math.h>

constexpr int NN = 10000;
constexpr int EE = 320000;
constexpr int H  = 4;
constexpr int D  = 64;
constexpr int C  = 16;
constexpr int IN = 256;
constexpr int HD = H * D; // 256

typedef __attribute__((ext_vector_type(8))) short bf16x8;
typedef __attribute__((ext_vector_type(4))) float f32x4;

__device__ __forceinline__ unsigned short f2b(float x) {
    unsigned int b = __float_as_uint(x);
    return (unsigned short)((b + 0x7FFFu + ((b >> 16) & 1u)) >> 16); // RNE bf16
}

// ---- workspace layout (float-element offsets) ----
constexpr long OFF_FEAT = 0;                               // N*HD f32
constexpr long OFF_FB   = OFF_FEAT + (long)NN * HD;        // N*HD bf16 = N*HD/2 floats
constexpr long OFF_EL   = OFF_FB   + (long)NN * HD / 2;    // N*H
constexpr long OFF_ER   = OFF_EL   + (long)NN * H;         // N*H
constexpr long OFF_F1   = OFF_ER   + (long)NN * H;         // N*H
constexpr long OFF_F2   = OFF_F1   + (long)NN * H;         // N*H
constexpr long OFF_AGG  = OFF_F2   + (long)NN * H;         // N*HD
constexpr long OFF_PRED = OFF_AGG  + (long)NN * HD;        // N   (int)
constexpr long OFF_SSRC = OFF_PRED + (long)NN;             // E   (int) src sorted by dst
constexpr long OFF_ROWP = OFF_SSRC + (long)EE;             // N+1 (int)
constexpr long OFF_CURS = OFF_ROWP + (long)NN + 1;         // N   (int)
constexpr long OFF_DEGI = OFF_CURS + (long)NN;             // N   (int, zeroed per call)
constexpr long OFF_SUM  = OFF_DEGI + (long)NN;             // 4 f32 (plain-stored by k_sum)
constexpr long OFF_WP   = OFF_SUM  + 4;                    // 65536 bf16 = 32768 floats
constexpr long WS_END   = OFF_WP + 32768;

constexpr int GEMB = (NN + 31) / 32;   // 313 MFMA-gemm blocks (32 rows each)
constexpr int PB   = (NN + 255) / 256; // 40 pred blocks
constexpr int CB   = (EE + 255) / 256; // 1250 count blocks

// pre-pack W into B-fragment order for mfma_f32_16x16x32_bf16:
// wp[((w*8+ks)*4+ct)*64 + l][i] = bf16( W[(ks*32+(l>>4)*8+i)*HD + w*64+ct*16+(l&15)] )
__global__ __launch_bounds__(256) void k_pack(const float* __restrict__ W,
                                              unsigned short* __restrict__ wp) {
    int tg = blockIdx.x * 256 + threadIdx.x; // [0, 8192)
    int l  = tg & 63;
    int ct = (tg >> 6) & 3;
    int ks = (tg >> 8) & 7;
    int w  = tg >> 11;
    int col = w * 64 + ct * 16 + (l & 15);
    int kb  = ks * 32 + (l >> 4) * 8;
    unsigned short v[8];
#pragma unroll
    for (int i = 0; i < 8; ++i) v[i] = f2b(W[(long)(kb + i) * HD + col]);
    ushort4* p = (ushort4*)(wp + (long)tg * 8);
    p[0] = make_ushort4(v[0], v[1], v[2], v[3]);
    p[1] = make_ushort4(v[4], v[5], v[6], v[7]);
}

// fused main kernel: blocks [0,GEMB) MFMA gemm, [GEMB,GEMB+PB) pred, rest count.
// GEMM: bf16 MFMA 16x16x32, f32 accumulate. Block = 32 rows x 256 cols;
// wave = one head (64 cols) -> 2 row-tiles x 4 col-tiles, 8 K-steps.
// el/er reduced from C-fragments (D layout: row=(l>>4)*4+reg, col=l&15).
__global__ __launch_bounds__(256) void k_main(const float* __restrict__ hin,
                                              const unsigned short* __restrict__ wp,
                                              const float* __restrict__ al,
                                              const float* __restrict__ ar,
                                              const float* __restrict__ logits,
                                              const int*   __restrict__ dst,
                                              float* __restrict__ feat,
                                              unsigned short* __restrict__ featb,
                                              float* __restrict__ el,
                                              float* __restrict__ er,
                                              int*   __restrict__ pred,
                                              int*   __restrict__ deg_i) {
    int bid = blockIdx.x;
    int t = threadIdx.x;
    if (bid < GEMB) {
        int n0 = bid * 32;
        int w = t >> 6, l = t & 63;
        int g = l >> 4, fr = l & 15;

        f32x4 acc[2][4];
#pragma unroll
        for (int m = 0; m < 2; ++m)
#pragma unroll
            for (int ct = 0; ct < 4; ++ct) acc[m][ct] = (f32x4){0.f, 0.f, 0.f, 0.f};

        int arow[2];
        arow[0] = n0 + fr;      if (arow[0] >= NN) arow[0] = NN - 1;
        arow[1] = n0 + 16 + fr; if (arow[1] >= NN) arow[1] = NN - 1;

        const unsigned short* wpw = wp + (long)w * 8 * 4 * 64 * 8;

        for (int ks = 0; ks < 8; ++ks) {
            bf16x8 af[2];
#pragma unroll
            for (int m = 0; m < 2; ++m) {
                const float* ap = hin + (long)arow[m] * IN + ks * 32 + g * 8;
                float4 a0 = *(const float4*)(ap);
                float4 a1 = *(const float4*)(ap + 4);
                bf16x8 v;
                v[0] = (short)f2b(a0.x); v[1] = (short)f2b(a0.y);
                v[2] = (short)f2b(a0.z); v[3] = (short)f2b(a0.w);
                v[4] = (short)f2b(a1.x); v[5] = (short)f2b(a1.y);
                v[6] = (short)f2b(a1.z); v[7] = (short)f2b(a1.w);
                af[m] = v;
            }
#pragma unroll
            for (int ct = 0; ct < 4; ++ct) {
                bf16x8 bfr = *(const bf16x8*)(wpw + (((long)ks * 4 + ct) * 64 + l) * 8);
                acc[0][ct] = __builtin_amdgcn_mfma_f32_16x16x32_bf16(af[0], bfr, acc[0][ct], 0, 0, 0);
                acc[1][ct] = __builtin_amdgcn_mfma_f32_16x16x32_bf16(af[1], bfr, acc[1][ct], 0, 0, 0);
            }
        }

        float aLr[4], aRr[4];
#pragma unroll
        for (int ct = 0; ct < 4; ++ct) {
            aLr[ct] = al[w * 64 + ct * 16 + fr];
            aRr[ct] = ar[w * 64 + ct * 16 + fr];
        }
#pragma unroll
        for (int m = 0; m < 2; ++m)
#pragma unroll
            for (int j = 0; j < 4; ++j) {
                int row = n0 + m * 16 + g * 4 + j;
                bool ok = row < NN;
                float vl = 0.f, vr = 0.f;
#pragma unroll
                for (int ct = 0; ct < 4; ++ct) {
                    float v = acc[m][ct][j];
                    if (ok) {
                        feat [(long)row * HD + w * 64 + ct * 16 + fr] = v;
                        featb[(long)row * HD + w * 64 + ct * 16 + fr] = f2b(v);
                    }
                    vl = fmaf(v, aLr[ct], vl);
                    vr = fmaf(v, aRr[ct], vr);
                }
                vl += __shfl_xor(vl, 1); vl += __shfl_xor(vl, 2);
                vl += __shfl_xor(vl, 4); vl += __shfl_xor(vl, 8);
                vr += __shfl_xor(vr, 1); vr += __shfl_xor(vr, 2);
                vr += __shfl_xor(vr, 4); vr += __shfl_xor(vr, 8);
                if (ok && fr == 0) {
                    el[(long)row * H + w] = vl;
                    er[(long)row * H + w] = vr;
                }
            }
    } else if (bid < GEMB + PB) {
        // ---- pred = argmax(logits) ----
        int n = (bid - GEMB) * 256 + t;
        if (n < NN) {
            const float* row = logits + (long)n * C;
            float best = row[0]; int bi = 0;
#pragma unroll
            for (int c = 1; c < C; ++c) { float v = row[c]; if (v > best) { best = v; bi = c; } }
            pred[n] = bi;
        }
    } else {
        // ---- in-degree counting ----
        int e = (bid - GEMB - PB) * 256 + t;
        if (e < EE) atomicAdd(&deg_i[dst[e]], 1);
    }
}

// 1024-thread single-block exclusive scan -> rowptr, cursor
__global__ __launch_bounds__(1024) void k_scan(const int* __restrict__ deg_i,
                                               int* __restrict__ rowptr,
                                               int* __restrict__ cursor) {
    __shared__ int lsum[1024];
    constexpr int CH = (NN + 1023) / 1024; // 10
    int t = threadIdx.x;
    int base = t * CH;
    int s = 0;
#pragma unroll
    for (int i = 0; i < CH; ++i) { int idx = base + i; if (idx < NN) s += deg_i[idx]; }
    lsum[t] = s;
    __syncthreads();
    for (int off = 1; off < 1024; off <<= 1) {
        int v = (t >= off) ? lsum[t - off] : 0;
        __syncthreads();
        lsum[t] += v;
        __syncthreads();
    }
    int run = t ? lsum[t - 1] : 0;
#pragma unroll
    for (int i = 0; i < CH; ++i) {
        int idx = base + i;
        if (idx < NN) { rowptr[idx] = run; cursor[idx] = run; run += deg_i[idx]; }
    }
    if (t == 1023) rowptr[NN] = lsum[1023];
}

__global__ __launch_bounds__(256) void k_scatter(const int* __restrict__ src,
                                                 const int* __restrict__ dst,
                                                 int* __restrict__ cursor,
                                                 int* __restrict__ ssrc) {
    int e = blockIdx.x * 256 + threadIdx.x;
    if (e >= EE) return;
    int d = dst[e];
    int pos = atomicAdd(&cursor[d], 1);
    ssrc[pos] = src[e];
}

// one wave per dst node. 16-edge strips; per-edge (src,pred) broadcast via
// readlane (scalar-uniform gather address) + 1 shfl for the weight.
// feat gathered in bf16 (512B/row) to halve L2-miss traffic.
#define EDGE(kk) { \
    int spk = __builtin_amdgcn_readlane(sp, (kk)); \
    int s_  = spk & 0xFFFF; \
    int ps_ = spk >> 16; \
    float wa = __shfl(w, (hidx << 4) | (kk)); \
    const ushort4 f = *(const ushort4*)(featb + (long)s_ * HD + (lane << 2)); \
    acc.x = fmaf(wa, __uint_as_float((unsigned int)f.x << 16), acc.x); \
    acc.y = fmaf(wa, __uint_as_float((unsigned int)f.y << 16), acc.y); \
    acc.z = fmaf(wa, __uint_as_float((unsigned int)f.z << 16), acc.z); \
    acc.w = fmaf(wa, __uint_as_float((unsigned int)f.w << 16), acc.w); \
    f1a += (ps_ == pd)   ? wa : 0.f; \
    ca  += (ps_ == cidx) ? wa : 0.f; \
}

__global__ __launch_bounds__(256) void k_agg(const int* __restrict__ rowptr,
                                             const int* __restrict__ ssrc,
                                             const float* __restrict__ el,
                                             const float* __restrict__ er,
                                             const unsigned short* __restrict__ featb,
                                             const int* __restrict__ pred,
                                             float* __restrict__ agg,
                                             float* __restrict__ f1,
                                             float* __restrict__ f2) {
    int lane = threadIdx.x & 63;
    int n = blockIdx.x * 4 + (threadIdx.x >> 6); // grid = NN/4 exactly
    int beg = rowptr[n], end = rowptr[n + 1];
    int deg = end - beg;
    int hidx = lane >> 4, cidx = lane & 15;
    float Rh = er[(long)n * H + hidx];
    int pd = pred[n];

    float4 acc = {0.f, 0.f, 0.f, 0.f};
    float dsum = 0.f, f1a = 0.f, ca = 0.f;

    for (int base = beg; base < end; base += 16) {
        int nk = end - base; if (nk > 16) nk = 16;
        float w = 0.f; int sp = 0;
        if (cidx < nk) {
            int s = ssrc[base + cidx];
            float x = el[(long)s * H + hidx] + Rh;
            x = x > 0.f ? x : 0.2f * x;
            w = __expf(x);
            if (hidx == 0) sp = s | (pred[s] << 16);
        }
        dsum += w;
        if (nk == 16) {
#pragma unroll
            for (int k = 0; k < 16; ++k) EDGE(k)
        } else {
            for (int k = 0; k < nk; ++k) EDGE(k)
        }
    }

    // per-head softmax denominator: reduce over the 16-lane group
    for (int off = 1; off < 16; off <<= 1) dsum += __shfl_xor(dsum, off);
    float invh = dsum > 0.f ? 1.f / dsum : 0.f;
    float invdeg = 1.0f / (float)(deg > 0 ? deg : 1);

    float4 o;
    o.x = acc.x * invh; o.y = acc.y * invh; o.z = acc.z * invh; o.w = acc.w * invh;
    *(float4*)(agg + (long)n * HD + (lane << 2)) = o;

    // f2 entropy term: lane (h,c) holds its class sum. (Globally-absent
    // classes contribute a constant that cancels in the global LayerNorm.)
    float v = fmaxf(ca * invh * invdeg, 1e-5f);
    float term = -v * logf(v);
    for (int off = 1; off < 16; off <<= 1) term += __shfl_xor(term, off);
    if (cidx == 0) {
        f1[(long)n * H + hidx] = f1a * invh * invdeg;
        f2[(long)n * H + hidx] = term;
    }
}

// single-block reduction of f1/f2 -> sums[4] (plain stores, deterministic)
__global__ __launch_bounds__(1024) void k_sum(const float* __restrict__ f1,
                                              const float* __restrict__ f2,
                                              float* __restrict__ sums) {
    __shared__ float red[16][4];
    float s1 = 0.f, q1 = 0.f, s2 = 0.f, q2 = 0.f;
    for (int i = threadIdx.x; i < NN * H; i += 1024) {
        float a = f1[i], b = f2[i];
        s1 += a; q1 = fmaf(a, a, q1);
        s2 += b; q2 = fmaf(b, b, q2);
    }
    for (int off = 32; off; off >>= 1) {
        s1 += __shfl_down(s1, off);
        q1 += __shfl_down(q1, off);
        s2 += __shfl_down(s2, off);
        q2 += __shfl_down(q2, off);
    }
    int wid = threadIdx.x >> 6;
    if ((threadIdx.x & 63) == 0) {
        red[wid][0] = s1; red[wid][1] = q1; red[wid][2] = s2; red[wid][3] = q2;
    }
    __syncthreads();
    if (threadIdx.x < 4) {
        float a = 0.f;
        for (int wv = 0; wv < 16; ++wv) a += red[wv][threadIdx.x];
        sums[threadIdx.x] = a;
    }
}

// fused: z/gate (LayerNorm'd f1,f2) + final output
__global__ __launch_bounds__(256) void k_out(const float* __restrict__ feat,
                                             const float* __restrict__ agg,
                                             const float* __restrict__ f1,
                                             const float* __restrict__ f2,
                                             const float* __restrict__ sums,
                                             const float* __restrict__ old_z,
                                             const float* __restrict__ tau1,
                                             const float* __restrict__ tau2,
                                             const int* __restrict__ rowptr,
                                             float* __restrict__ out,
                                             float* __restrict__ zout) {
    long i = (long)blockIdx.x * 256 + threadIdx.x;
    if (i >= (long)NN * HD) return;
    int n = (int)(i >> 8);
    int h = (int)((i >> 6) & 3);
    int t = n * H + h;
    constexpr float invNH = 1.0f / (NN * H);
    float mu1 = sums[0] * invNH, mu2 = sums[2] * invNH;
    float v1 = fmaxf(sums[1] * invNH - mu1 * mu1, 0.f);
    float v2 = fmaxf(sums[3] * invNH - mu2 * mu2, 0.f);
    float r1 = rsqrtf(v1 + 1e-5f), r2 = rsqrtf(v2 + 1e-5f);
    float nf1 = (f1[t] - mu1) * r1;
    float nf2 = (f2[t] - mu2) * r2;
    float z = (1.f / (1.f + expf(nf1 - tau1[0]))) * (1.f / (1.f + expf(nf2 - tau2[0])));
    float gate = fminf(old_z[t], z);
    if ((i & 63) == 0) zout[t] = z;
    int deg = rowptr[n + 1] - rowptr[n];
    float nrm = rsqrtf((float)(deg > 0 ? deg : 1));
    out[i] = feat[i] + gate * agg[i] * nrm;
}

extern "C" void kernel_launch(void* const* d_in, const int* in_sizes, int n_in,
                              void* d_out, int out_size, void* d_ws, size_t ws_size,
                              hipStream_t stream) {
    const float* hin    = (const float*)d_in[0];
    const float* logits = (const float*)d_in[1];
    const float* old_z  = (const float*)d_in[2];
    const float* attn_l = (const float*)d_in[3];
    const float* attn_r = (const float*)d_in[4];
    const float* Wfc    = (const float*)d_in[5];
    const float* tau1   = (const float*)d_in[6];
    const float* tau2   = (const float*)d_in[7];
    const int*   src    = (const int*)d_in[8];
    const int*   dst    = (const int*)d_in[9];
    float* out = (float*)d_out;
    float* ws  = (float*)d_ws;

    unsigned short* featb = (unsigned short*)(ws + OFF_FB);
    unsigned short* wp    = (unsigned short*)(ws + OFF_WP);
    int* pred   = (int*)(ws + OFF_PRED);
    int* ssrc   = (int*)(ws + OFF_SSRC);
    int* rowptr = (int*)(ws + OFF_ROWP);
    int* cursor = (int*)(ws + OFF_CURS);
    int* deg_i  = (int*)(ws + OFF_DEGI);
    float* sums = ws + OFF_SUM;

    // zero only the degree counters
    hipMemsetAsync(deg_i, 0, (size_t)NN * sizeof(int), stream);

    k_pack   <<<32, 256, 0, stream>>>(Wfc, wp);
    k_main   <<<GEMB + PB + CB, 256, 0, stream>>>(hin, wp, attn_l, attn_r, logits, dst,
                                                  ws + OFF_FEAT, featb,
                                                  ws + OFF_EL, ws + OFF_ER,
                                                  pred, deg_i);
    k_scan   <<<1, 1024, 0, stream>>>(deg_i, rowptr, cursor);
    k_scatter<<<(EE + 255) / 256, 256, 0, stream>>>(src, dst, cursor, ssrc);
    k_agg    <<<NN / 4, 256, 0, stream>>>(rowptr, ssrc, ws + OFF_EL, ws + OFF_ER,
                                          featb, pred,
                                          ws + OFF_AGG, ws + OFF_F1, ws + OFF_F2);
    k_sum    <<<1, 1024, 0, stream>>>(ws + OFF_F1, ws + OFF_F2, sums);
    k_out    <<<(NN * HD + 255) / 256, 256, 0, stream>>>(ws + OFF_FEAT, ws + OFF_AGG,
                                                         ws + OFF_F1, ws + OFF_F2, sums,
                                                         old_z, tau1, tau2, rowptr,
                                                         out, out + (long)NN * HD);
}

// Round 9
// 122.548 us; speedup vs baseline: 10.8272x; 1.0533x over previous
//
#include <hip/hip_runtime.h>
#include <math.h>

constexpr int NN = 10000;
constexpr int EE = 320000;
constexpr int H  = 4;
constexpr int D  = 64;
constexpr int C  = 16;
constexpr int IN = 256;
constexpr int HD = H * D; // 256

typedef __attribute__((ext_vector_type(8))) short bf16x8;
typedef __attribute__((ext_vector_type(4))) float f32x4;

__device__ __forceinline__ unsigned short f2b(float x) {
    unsigned int b = __float_as_uint(x);
    return (unsigned short)((b + 0x7FFFu + ((b >> 16) & 1u)) >> 16); // RNE bf16
}

// ---- workspace layout (float-element offsets) ----
constexpr long OFF_FEAT = 0;                               // N*HD f32
constexpr long OFF_FB   = OFF_FEAT + (long)NN * HD;        // N*HD bf16 = N*HD/2 floats
constexpr long OFF_EL   = OFF_FB   + (long)NN * HD / 2;    // N*H
constexpr long OFF_ER   = OFF_EL   + (long)NN * H;         // N*H
constexpr long OFF_F1   = OFF_ER   + (long)NN * H;         // N*H
constexpr long OFF_F2   = OFF_F1   + (long)NN * H;         // N*H
constexpr long OFF_AGG  = OFF_F2   + (long)NN * H;         // N*HD
constexpr long OFF_PRED = OFF_AGG  + (long)NN * HD;        // N   (int)
constexpr long OFF_SSRC = OFF_PRED + (long)NN;             // E   (int) src sorted by dst
constexpr long OFF_ROWP = OFF_SSRC + (long)EE;             // N+1 (int)
constexpr long OFF_CURS = OFF_ROWP + (long)NN + 1;         // N   (int)
constexpr long OFF_DEGI = OFF_CURS + (long)NN;             // N   (int, zeroed by k_pack)
constexpr long OFF_SUM  = OFF_DEGI + (long)NN;             // 4 f32 (plain-stored by k_sum)
constexpr long OFF_WP   = OFF_SUM  + 4;                    // 65536 bf16 = 32768 floats
constexpr long WS_END   = OFF_WP + 32768;

constexpr int GEMB = (NN + 31) / 32;   // 313 MFMA-gemm blocks (32 rows each)
constexpr int PB   = (NN + 255) / 256; // 40 pred blocks
constexpr int CB   = (EE + 255) / 256; // 1250 count blocks
constexpr int ZB   = (NN + 255) / 256; // 40 zero blocks (in k_pack)

// blocks [0,32): pre-pack W into B-fragment order for mfma_f32_16x16x32_bf16.
// blocks [32,32+ZB): zero deg_i (replaces a pathologically slow 43us
// hipMemsetAsync fill dispatch observed in rocprof).
__global__ __launch_bounds__(256) void k_pack(const float* __restrict__ W,
                                              unsigned short* __restrict__ wp,
                                              int* __restrict__ deg_i) {
    if (blockIdx.x >= 32) {
        int n = (blockIdx.x - 32) * 256 + threadIdx.x;
        if (n < NN) deg_i[n] = 0;
        return;
    }
    int tg = blockIdx.x * 256 + threadIdx.x; // [0, 8192)
    int l  = tg & 63;
    int ct = (tg >> 6) & 3;
    int ks = (tg >> 8) & 7;
    int w  = tg >> 11;
    int col = w * 64 + ct * 16 + (l & 15);
    int kb  = ks * 32 + (l >> 4) * 8;
    unsigned short v[8];
#pragma unroll
    for (int i = 0; i < 8; ++i) v[i] = f2b(W[(long)(kb + i) * HD + col]);
    ushort4* p = (ushort4*)(wp + (long)tg * 8);
    p[0] = make_ushort4(v[0], v[1], v[2], v[3]);
    p[1] = make_ushort4(v[4], v[5], v[6], v[7]);
}

// fused main kernel: blocks [0,GEMB) MFMA gemm, [GEMB,GEMB+PB) pred, rest count.
// GEMM: bf16 MFMA 16x16x32, f32 accumulate. Block = 32 rows x 256 cols;
// wave = one head (64 cols) -> 2 row-tiles x 4 col-tiles, 8 K-steps.
// el/er reduced from C-fragments (D layout: row=(l>>4)*4+reg, col=l&15).
__global__ __launch_bounds__(256) void k_main(const float* __restrict__ hin,
                                              const unsigned short* __restrict__ wp,
                                              const float* __restrict__ al,
                                              const float* __restrict__ ar,
                                              const float* __restrict__ logits,
                                              const int*   __restrict__ dst,
                                              float* __restrict__ feat,
                                              unsigned short* __restrict__ featb,
                                              float* __restrict__ el,
                                              float* __restrict__ er,
                                              int*   __restrict__ pred,
                                              int*   __restrict__ deg_i) {
    int bid = blockIdx.x;
    int t = threadIdx.x;
    if (bid < GEMB) {
        int n0 = bid * 32;
        int w = t >> 6, l = t & 63;
        int g = l >> 4, fr = l & 15;

        f32x4 acc[2][4];
#pragma unroll
        for (int m = 0; m < 2; ++m)
#pragma unroll
            for (int ct = 0; ct < 4; ++ct) acc[m][ct] = (f32x4){0.f, 0.f, 0.f, 0.f};

        int arow[2];
        arow[0] = n0 + fr;      if (arow[0] >= NN) arow[0] = NN - 1;
        arow[1] = n0 + 16 + fr; if (arow[1] >= NN) arow[1] = NN - 1;

        const unsigned short* wpw = wp + (long)w * 8 * 4 * 64 * 8;

        for (int ks = 0; ks < 8; ++ks) {
            bf16x8 af[2];
#pragma unroll
            for (int m = 0; m < 2; ++m) {
                const float* ap = hin + (long)arow[m] * IN + ks * 32 + g * 8;
                float4 a0 = *(const float4*)(ap);
                float4 a1 = *(const float4*)(ap + 4);
                bf16x8 v;
                v[0] = (short)f2b(a0.x); v[1] = (short)f2b(a0.y);
                v[2] = (short)f2b(a0.z); v[3] = (short)f2b(a0.w);
                v[4] = (short)f2b(a1.x); v[5] = (short)f2b(a1.y);
                v[6] = (short)f2b(a1.z); v[7] = (short)f2b(a1.w);
                af[m] = v;
            }
#pragma unroll
            for (int ct = 0; ct < 4; ++ct) {
                bf16x8 bfr = *(const bf16x8*)(wpw + (((long)ks * 4 + ct) * 64 + l) * 8);
                acc[0][ct] = __builtin_amdgcn_mfma_f32_16x16x32_bf16(af[0], bfr, acc[0][ct], 0, 0, 0);
                acc[1][ct] = __builtin_amdgcn_mfma_f32_16x16x32_bf16(af[1], bfr, acc[1][ct], 0, 0, 0);
            }
        }

        float aLr[4], aRr[4];
#pragma unroll
        for (int ct = 0; ct < 4; ++ct) {
            aLr[ct] = al[w * 64 + ct * 16 + fr];
            aRr[ct] = ar[w * 64 + ct * 16 + fr];
        }
#pragma unroll
        for (int m = 0; m < 2; ++m)
#pragma unroll
            for (int j = 0; j < 4; ++j) {
                int row = n0 + m * 16 + g * 4 + j;
                bool ok = row < NN;
                float vl = 0.f, vr = 0.f;
#pragma unroll
                for (int ct = 0; ct < 4; ++ct) {
                    float v = acc[m][ct][j];
                    if (ok) {
                        feat [(long)row * HD + w * 64 + ct * 16 + fr] = v;
                        featb[(long)row * HD + w * 64 + ct * 16 + fr] = f2b(v);
                    }
                    vl = fmaf(v, aLr[ct], vl);
                    vr = fmaf(v, aRr[ct], vr);
                }
                vl += __shfl_xor(vl, 1); vl += __shfl_xor(vl, 2);
                vl += __shfl_xor(vl, 4); vl += __shfl_xor(vl, 8);
                vr += __shfl_xor(vr, 1); vr += __shfl_xor(vr, 2);
                vr += __shfl_xor(vr, 4); vr += __shfl_xor(vr, 8);
                if (ok && fr == 0) {
                    el[(long)row * H + w] = vl;
                    er[(long)row * H + w] = vr;
                }
            }
    } else if (bid < GEMB + PB) {
        // ---- pred = argmax(logits) ----
        int n = (bid - GEMB) * 256 + t;
        if (n < NN) {
            const float* row = logits + (long)n * C;
            float best = row[0]; int bi = 0;
#pragma unroll
            for (int c = 1; c < C; ++c) { float v = row[c]; if (v > best) { best = v; bi = c; } }
            pred[n] = bi;
        }
    } else {
        // ---- in-degree counting ----
        int e = (bid - GEMB - PB) * 256 + t;
        if (e < EE) atomicAdd(&deg_i[dst[e]], 1);
    }
}

// 1024-thread single-block exclusive scan -> rowptr, cursor
__global__ __launch_bounds__(1024) void k_scan(const int* __restrict__ deg_i,
                                               int* __restrict__ rowptr,
                                               int* __restrict__ cursor) {
    __shared__ int lsum[1024];
    constexpr int CH = (NN + 1023) / 1024; // 10
    int t = threadIdx.x;
    int base = t * CH;
    int s = 0;
#pragma unroll
    for (int i = 0; i < CH; ++i) { int idx = base + i; if (idx < NN) s += deg_i[idx]; }
    lsum[t] = s;
    __syncthreads();
    for (int off = 1; off < 1024; off <<= 1) {
        int v = (t >= off) ? lsum[t - off] : 0;
        __syncthreads();
        lsum[t] += v;
        __syncthreads();
    }
    int run = t ? lsum[t - 1] : 0;
#pragma unroll
    for (int i = 0; i < CH; ++i) {
        int idx = base + i;
        if (idx < NN) { rowptr[idx] = run; cursor[idx] = run; run += deg_i[idx]; }
    }
    if (t == 1023) rowptr[NN] = lsum[1023];
}

__global__ __launch_bounds__(256) void k_scatter(const int* __restrict__ src,
                                                 const int* __restrict__ dst,
                                                 int* __restrict__ cursor,
                                                 int* __restrict__ ssrc) {
    int e = blockIdx.x * 256 + threadIdx.x;
    if (e >= EE) return;
    int d = dst[e];
    int pos = atomicAdd(&cursor[d], 1);
    ssrc[pos] = src[e];
}

// one wave per dst node. 16-edge strips; per-edge (src,pred) broadcast via
// readlane (scalar-uniform gather address) + 1 shfl for the weight.
// feat gathered in bf16 (512B/row) to halve L2-miss traffic.
#define EDGE(kk) { \
    int spk = __builtin_amdgcn_readlane(sp, (kk)); \
    int s_  = spk & 0xFFFF; \
    int ps_ = spk >> 16; \
    float wa = __shfl(w, (hidx << 4) | (kk)); \
    const ushort4 f = *(const ushort4*)(featb + (long)s_ * HD + (lane << 2)); \
    acc.x = fmaf(wa, __uint_as_float((unsigned int)f.x << 16), acc.x); \
    acc.y = fmaf(wa, __uint_as_float((unsigned int)f.y << 16), acc.y); \
    acc.z = fmaf(wa, __uint_as_float((unsigned int)f.z << 16), acc.z); \
    acc.w = fmaf(wa, __uint_as_float((unsigned int)f.w << 16), acc.w); \
    f1a += (ps_ == pd)   ? wa : 0.f; \
    ca  += (ps_ == cidx) ? wa : 0.f; \
}

__global__ __launch_bounds__(256) void k_agg(const int* __restrict__ rowptr,
                                             const int* __restrict__ ssrc,
                                             const float* __restrict__ el,
                                             const float* __restrict__ er,
                                             const unsigned short* __restrict__ featb,
                                             const int* __restrict__ pred,
                                             float* __restrict__ agg,
                                             float* __restrict__ f1,
                                             float* __restrict__ f2) {
    int lane = threadIdx.x & 63;
    int n = blockIdx.x * 4 + (threadIdx.x >> 6); // grid = NN/4 exactly
    int beg = rowptr[n], end = rowptr[n + 1];
    int deg = end - beg;
    int hidx = lane >> 4, cidx = lane & 15;
    float Rh = er[(long)n * H + hidx];
    int pd = pred[n];

    float4 acc = {0.f, 0.f, 0.f, 0.f};
    float dsum = 0.f, f1a = 0.f, ca = 0.f;

    for (int base = beg; base < end; base += 16) {
        int nk = end - base; if (nk > 16) nk = 16;
        float w = 0.f; int sp = 0;
        if (cidx < nk) {
            int s = ssrc[base + cidx];
            float x = el[(long)s * H + hidx] + Rh;
            x = x > 0.f ? x : 0.2f * x;
            w = __expf(x);
            if (hidx == 0) sp = s | (pred[s] << 16);
        }
        dsum += w;
        if (nk == 16) {
#pragma unroll
            for (int k = 0; k < 16; ++k) EDGE(k)
        } else {
            for (int k = 0; k < nk; ++k) EDGE(k)
        }
    }

    // per-head softmax denominator: reduce over the 16-lane group
    for (int off = 1; off < 16; off <<= 1) dsum += __shfl_xor(dsum, off);
    float invh = dsum > 0.f ? 1.f / dsum : 0.f;
    float invdeg = 1.0f / (float)(deg > 0 ? deg : 1);

    float4 o;
    o.x = acc.x * invh; o.y = acc.y * invh; o.z = acc.z * invh; o.w = acc.w * invh;
    *(float4*)(agg + (long)n * HD + (lane << 2)) = o;

    // f2 entropy term: lane (h,c) holds its class sum. (Globally-absent
    // classes contribute a constant that cancels in the global LayerNorm.)
    float v = fmaxf(ca * invh * invdeg, 1e-5f);
    float term = -v * logf(v);
    for (int off = 1; off < 16; off <<= 1) term += __shfl_xor(term, off);
    if (cidx == 0) {
        f1[(long)n * H + hidx] = f1a * invh * invdeg;
        f2[(long)n * H + hidx] = term;
    }
}

// single-block reduction of f1/f2 -> sums[4] (plain stores, deterministic)
__global__ __launch_bounds__(1024) void k_sum(const float* __restrict__ f1,
                                              const float* __restrict__ f2,
                                              float* __restrict__ sums) {
    __shared__ float red[16][4];
    float s1 = 0.f, q1 = 0.f, s2 = 0.f, q2 = 0.f;
    for (int i = threadIdx.x; i < NN * H; i += 1024) {
        float a = f1[i], b = f2[i];
        s1 += a; q1 = fmaf(a, a, q1);
        s2 += b; q2 = fmaf(b, b, q2);
    }
    for (int off = 32; off; off >>= 1) {
        s1 += __shfl_down(s1, off);
        q1 += __shfl_down(q1, off);
        s2 += __shfl_down(s2, off);
        q2 += __shfl_down(q2, off);
    }
    int wid = threadIdx.x >> 6;
    if ((threadIdx.x & 63) == 0) {
        red[wid][0] = s1; red[wid][1] = q1; red[wid][2] = s2; red[wid][3] = q2;
    }
    __syncthreads();
    if (threadIdx.x < 4) {
        float a = 0.f;
        for (int wv = 0; wv < 16; ++wv) a += red[wv][threadIdx.x];
        sums[threadIdx.x] = a;
    }
}

// fused: z/gate (LayerNorm'd f1,f2) + final output
__global__ __launch_bounds__(256) void k_out(const float* __restrict__ feat,
                                             const float* __restrict__ agg,
                                             const float* __restrict__ f1,
                                             const float* __restrict__ f2,
                                             const float* __restrict__ sums,
                                             const float* __restrict__ old_z,
                                             const float* __restrict__ tau1,
                                             const float* __restrict__ tau2,
                                             const int* __restrict__ rowptr,
                                             float* __restrict__ out,
                                             float* __restrict__ zout) {
    long i = (long)blockIdx.x * 256 + threadIdx.x;
    if (i >= (long)NN * HD) return;
    int n = (int)(i >> 8);
    int h = (int)((i >> 6) & 3);
    int t = n * H + h;
    constexpr float invNH = 1.0f / (NN * H);
    float mu1 = sums[0] * invNH, mu2 = sums[2] * invNH;
    float v1 = fmaxf(sums[1] * invNH - mu1 * mu1, 0.f);
    float v2 = fmaxf(sums[3] * invNH - mu2 * mu2, 0.f);
    float r1 = rsqrtf(v1 + 1e-5f), r2 = rsqrtf(v2 + 1e-5f);
    float nf1 = (f1[t] - mu1) * r1;
    float nf2 = (f2[t] - mu2) * r2;
    float z = (1.f / (1.f + expf(nf1 - tau1[0]))) * (1.f / (1.f + expf(nf2 - tau2[0])));
    float gate = fminf(old_z[t], z);
    if ((i & 63) == 0) zout[t] = z;
    int deg = rowptr[n + 1] - rowptr[n];
    float nrm = rsqrtf((float)(deg > 0 ? deg : 1));
    out[i] = feat[i] + gate * agg[i] * nrm;
}

extern "C" void kernel_launch(void* const* d_in, const int* in_sizes, int n_in,
                              void* d_out, int out_size, void* d_ws, size_t ws_size,
                              hipStream_t stream) {
    const float* hin    = (const float*)d_in[0];
    const float* logits = (const float*)d_in[1];
    const float* old_z  = (const float*)d_in[2];
    const float* attn_l = (const float*)d_in[3];
    const float* attn_r = (const float*)d_in[4];
    const float* Wfc    = (const float*)d_in[5];
    const float* tau1   = (const float*)d_in[6];
    const float* tau2   = (const float*)d_in[7];
    const int*   src    = (const int*)d_in[8];
    const int*   dst    = (const int*)d_in[9];
    float* out = (float*)d_out;
    float* ws  = (float*)d_ws;

    unsigned short* featb = (unsigned short*)(ws + OFF_FB);
    unsigned short* wp    = (unsigned short*)(ws + OFF_WP);
    int* pred   = (int*)(ws + OFF_PRED);
    int* ssrc   = (int*)(ws + OFF_SSRC);
    int* rowptr = (int*)(ws + OFF_ROWP);
    int* cursor = (int*)(ws + OFF_CURS);
    int* deg_i  = (int*)(ws + OFF_DEGI);
    float* sums = ws + OFF_SUM;

    k_pack   <<<32 + ZB, 256, 0, stream>>>(Wfc, wp, deg_i);
    k_main   <<<GEMB + PB + CB, 256, 0, stream>>>(hin, wp, attn_l, attn_r, logits, dst,
                                                  ws + OFF_FEAT, featb,
                                                  ws + OFF_EL, ws + OFF_ER,
                                                  pred, deg_i);
    k_scan   <<<1, 1024, 0, stream>>>(deg_i, rowptr, cursor);
    k_scatter<<<(EE + 255) / 256, 256, 0, stream>>>(src, dst, cursor, ssrc);
    k_agg    <<<NN / 4, 256, 0, stream>>>(rowptr, ssrc, ws + OFF_EL, ws + OFF_ER,
                                          featb, pred,
                                          ws + OFF_AGG, ws + OFF_F1, ws + OFF_F2);
    k_sum    <<<1, 1024, 0, stream>>>(ws + OFF_F1, ws + OFF_F2, sums);
    k_out    <<<(NN * HD + 255) / 256, 256, 0, stream>>>(ws + OFF_FEAT, ws + OFF_AGG,
                                                         ws + OFF_F1, ws + OFF_F2, sums,
                                                         old_z, tau1, tau2, rowptr,
                                                         out, out + (long)NN * HD);
}

// Round 10
// 118.146 us; speedup vs baseline: 11.2307x; 1.0373x over previous
//
#include <hip/hip_runtime.h>
#include <math.h>

constexpr int NN = 10000;
constexpr int EE = 320000;
constexpr int H  = 4;
constexpr int D  = 64;
constexpr int C  = 16;
constexpr int IN = 256;
constexpr int HD = H * D; // 256

typedef __attribute__((ext_vector_type(8))) short bf16x8;
typedef __attribute__((ext_vector_type(4))) float f32x4;

__device__ __forceinline__ unsigned short f2b(float x) {
    unsigned int b = __float_as_uint(x);
    return (unsigned short)((b + 0x7FFFu + ((b >> 16) & 1u)) >> 16); // RNE bf16
}

// ---- workspace layout (float-element offsets) ----
constexpr long OFF_FEAT = 0;                               // N*HD f32
constexpr long OFF_FB   = OFF_FEAT + (long)NN * HD;        // N*HD bf16 = N*HD/2 floats
constexpr long OFF_EL   = OFF_FB   + (long)NN * HD / 2;    // N*H
constexpr long OFF_ER   = OFF_EL   + (long)NN * H;         // N*H
constexpr long OFF_F1   = OFF_ER   + (long)NN * H;         // N*H
constexpr long OFF_F2   = OFF_F1   + (long)NN * H;         // N*H
constexpr long OFF_AGG  = OFF_F2   + (long)NN * H;         // N*HD
constexpr long OFF_PRED = OFF_AGG  + (long)NN * HD;        // N   (int)
constexpr long OFF_SSRC = OFF_PRED + (long)NN;             // E   (int) src sorted by dst
constexpr long OFF_ROWP = OFF_SSRC + (long)EE;             // N+1 (int)
constexpr long OFF_CURS = OFF_ROWP + (long)NN + 1;         // N   (int)
constexpr long OFF_DEGI = OFF_CURS + (long)NN;             // N   (int, zeroed by k_pack)
constexpr long OFF_SUM  = OFF_DEGI + (long)NN;             // 4 f32 (plain-stored by k_sum)
constexpr long OFF_WP   = OFF_SUM  + 4;                    // 65536 bf16 = 32768 floats
constexpr long OFF_HA   = OFF_WP   + 32768;                // N*IN bf16 A-frag table = 1.28M floats
constexpr long WS_END   = OFF_HA + (long)NN * IN / 2;

constexpr int GEMB = NN / 16;          // 625 MFMA-gemm blocks (16 rows each, exact)
constexpr int PB   = (NN + 255) / 256; // 40 pred blocks
constexpr int CB   = (EE + 255) / 256; // 1250 count blocks
constexpr int ZB   = (NN + 255) / 256; // 40 zero blocks (in k_pack)
constexpr int HAB  = (NN / 16) * 8 * 64 / 256; // 1250 ha-transform blocks

// k_pack roles: [0,32) W->B-fragment pack; [32,32+ZB) zero deg_i;
// [32+ZB, ...) h -> bf16 A-fragment table ha (hoists the per-ks f32->bf16
// conversion out of k_main's MFMA loop; coalesced 16B/lane stores).
// ha[((tile*8 + ks)*64 + l)*8 + i] = bf16(h[tile*16 + (l&15)][ks*32 + (l>>4)*8 + i])
__global__ __launch_bounds__(256) void k_pack(const float* __restrict__ W,
                                              const float* __restrict__ hin,
                                              unsigned short* __restrict__ wp,
                                              unsigned short* __restrict__ ha,
                                              int* __restrict__ deg_i) {
    int bid = blockIdx.x;
    int t = threadIdx.x;
    if (bid < 32) {
        int tg = bid * 256 + t; // [0, 8192)
        int l  = tg & 63;
        int ct = (tg >> 6) & 3;
        int ks = (tg >> 8) & 7;
        int w  = tg >> 11;
        int col = w * 64 + ct * 16 + (l & 15);
        int kb  = ks * 32 + (l >> 4) * 8;
        unsigned short v[8];
#pragma unroll
        for (int i = 0; i < 8; ++i) v[i] = f2b(W[(long)(kb + i) * HD + col]);
        ushort4* p = (ushort4*)(wp + (long)tg * 8);
        p[0] = make_ushort4(v[0], v[1], v[2], v[3]);
        p[1] = make_ushort4(v[4], v[5], v[6], v[7]);
    } else if (bid < 32 + ZB) {
        int n = (bid - 32) * 256 + t;
        if (n < NN) deg_i[n] = 0;
    } else {
        int e = (bid - 32 - ZB) * 256 + t; // [0, 320000) exact
        int l = e & 63, ks = (e >> 6) & 7, tile = e >> 9;
        int row = tile * 16 + (l & 15);
        int k0  = ks * 32 + (l >> 4) * 8;
        const float* ap = hin + (long)row * IN + k0;
        float4 a0 = *(const float4*)(ap);
        float4 a1 = *(const float4*)(ap + 4);
        ushort4* p = (ushort4*)(ha + (long)e * 8);
        p[0] = make_ushort4(f2b(a0.x), f2b(a0.y), f2b(a0.z), f2b(a0.w));
        p[1] = make_ushort4(f2b(a1.x), f2b(a1.y), f2b(a1.z), f2b(a1.w));
    }
}

// fused main kernel: blocks [0,GEMB) MFMA gemm, [GEMB,GEMB+PB) pred, rest count.
// GEMM: bf16 MFMA 16x16x32, f32 accumulate. Block = 16 rows x 256 cols;
// wave = one head (64 cols) -> 4 col-tiles, 8 K-steps. A-frags preconverted
// (ha), one dwordx4 per ks, 1KB contiguous per wave, zero in-loop conversion.
__global__ __launch_bounds__(256) void k_main(const unsigned short* __restrict__ ha,
                                              const unsigned short* __restrict__ wp,
                                              const float* __restrict__ al,
                                              const float* __restrict__ ar,
                                              const float* __restrict__ logits,
                                              const int*   __restrict__ dst,
                                              float* __restrict__ feat,
                                              unsigned short* __restrict__ featb,
                                              float* __restrict__ el,
                                              float* __restrict__ er,
                                              int*   __restrict__ pred,
                                              int*   __restrict__ deg_i) {
    int bid = blockIdx.x;
    int t = threadIdx.x;
    if (bid < GEMB) {
        int tile = bid;
        int w = t >> 6, l = t & 63;
        int g = l >> 4, fr = l & 15;

        f32x4 acc[4];
#pragma unroll
        for (int ct = 0; ct < 4; ++ct) acc[ct] = (f32x4){0.f, 0.f, 0.f, 0.f};

        const unsigned short* wpw = wp + (long)w * 8 * 4 * 64 * 8;
        const unsigned short* hap = ha + (long)tile * 8 * 64 * 8;

        for (int ks = 0; ks < 8; ++ks) {
            bf16x8 af = *(const bf16x8*)(hap + ((long)ks * 64 + l) * 8);
#pragma unroll
            for (int ct = 0; ct < 4; ++ct) {
                bf16x8 bfr = *(const bf16x8*)(wpw + (((long)ks * 4 + ct) * 64 + l) * 8);
                acc[ct] = __builtin_amdgcn_mfma_f32_16x16x32_bf16(af, bfr, acc[ct], 0, 0, 0);
            }
        }

        float aLr[4], aRr[4];
#pragma unroll
        for (int ct = 0; ct < 4; ++ct) {
            aLr[ct] = al[w * 64 + ct * 16 + fr];
            aRr[ct] = ar[w * 64 + ct * 16 + fr];
        }
#pragma unroll
        for (int j = 0; j < 4; ++j) {
            int row = tile * 16 + g * 4 + j;
            float vl = 0.f, vr = 0.f;
#pragma unroll
            for (int ct = 0; ct < 4; ++ct) {
                float v = acc[ct][j];
                feat [(long)row * HD + w * 64 + ct * 16 + fr] = v;
                featb[(long)row * HD + w * 64 + ct * 16 + fr] = f2b(v);
                vl = fmaf(v, aLr[ct], vl);
                vr = fmaf(v, aRr[ct], vr);
            }
            vl += __shfl_xor(vl, 1); vl += __shfl_xor(vl, 2);
            vl += __shfl_xor(vl, 4); vl += __shfl_xor(vl, 8);
            vr += __shfl_xor(vr, 1); vr += __shfl_xor(vr, 2);
            vr += __shfl_xor(vr, 4); vr += __shfl_xor(vr, 8);
            if (fr == 0) {
                el[(long)row * H + w] = vl;
                er[(long)row * H + w] = vr;
            }
        }
    } else if (bid < GEMB + PB) {
        // ---- pred = argmax(logits) ----
        int n = (bid - GEMB) * 256 + t;
        if (n < NN) {
            const float* row = logits + (long)n * C;
            float best = row[0]; int bi = 0;
#pragma unroll
            for (int c = 1; c < C; ++c) { float v = row[c]; if (v > best) { best = v; bi = c; } }
            pred[n] = bi;
        }
    } else {
        // ---- in-degree counting ----
        int e = (bid - GEMB - PB) * 256 + t;
        if (e < EE) atomicAdd(&deg_i[dst[e]], 1);
    }
}

// 1024-thread single-block exclusive scan -> rowptr, cursor
__global__ __launch_bounds__(1024) void k_scan(const int* __restrict__ deg_i,
                                               int* __restrict__ rowptr,
                                               int* __restrict__ cursor) {
    __shared__ int lsum[1024];
    constexpr int CH = (NN + 1023) / 1024; // 10
    int t = threadIdx.x;
    int base = t * CH;
    int s = 0;
#pragma unroll
    for (int i = 0; i < CH; ++i) { int idx = base + i; if (idx < NN) s += deg_i[idx]; }
    lsum[t] = s;
    __syncthreads();
    for (int off = 1; off < 1024; off <<= 1) {
        int v = (t >= off) ? lsum[t - off] : 0;
        __syncthreads();
        lsum[t] += v;
        __syncthreads();
    }
    int run = t ? lsum[t - 1] : 0;
#pragma unroll
    for (int i = 0; i < CH; ++i) {
        int idx = base + i;
        if (idx < NN) { rowptr[idx] = run; cursor[idx] = run; run += deg_i[idx]; }
    }
    if (t == 1023) rowptr[NN] = lsum[1023];
}

__global__ __launch_bounds__(256) void k_scatter(const int* __restrict__ src,
                                                 const int* __restrict__ dst,
                                                 int* __restrict__ cursor,
                                                 int* __restrict__ ssrc) {
    int e = blockIdx.x * 256 + threadIdx.x;
    if (e >= EE) return;
    int d = dst[e];
    int pos = atomicAdd(&cursor[d], 1);
    ssrc[pos] = src[e];
}

// one wave per dst node. 16-edge strips; per-edge (src,pred) broadcast via
// readlane (scalar-uniform gather address) + 1 shfl for the weight.
// feat gathered in bf16 (512B/row) to halve L2-miss traffic.
#define EDGE(kk) { \
    int spk = __builtin_amdgcn_readlane(sp, (kk)); \
    int s_  = spk & 0xFFFF; \
    int ps_ = spk >> 16; \
    float wa = __shfl(w, (hidx << 4) | (kk)); \
    const ushort4 f = *(const ushort4*)(featb + (long)s_ * HD + (lane << 2)); \
    acc.x = fmaf(wa, __uint_as_float((unsigned int)f.x << 16), acc.x); \
    acc.y = fmaf(wa, __uint_as_float((unsigned int)f.y << 16), acc.y); \
    acc.z = fmaf(wa, __uint_as_float((unsigned int)f.z << 16), acc.z); \
    acc.w = fmaf(wa, __uint_as_float((unsigned int)f.w << 16), acc.w); \
    f1a += (ps_ == pd)   ? wa : 0.f; \
    ca  += (ps_ == cidx) ? wa : 0.f; \
}

__global__ __launch_bounds__(256) void k_agg(const int* __restrict__ rowptr,
                                             const int* __restrict__ ssrc,
                                             const float* __restrict__ el,
                                             const float* __restrict__ er,
                                             const unsigned short* __restrict__ featb,
                                             const int* __restrict__ pred,
                                             float* __restrict__ agg,
                                             float* __restrict__ f1,
                                             float* __restrict__ f2) {
    int lane = threadIdx.x & 63;
    int n = blockIdx.x * 4 + (threadIdx.x >> 6); // grid = NN/4 exactly
    int beg = rowptr[n], end = rowptr[n + 1];
    int deg = end - beg;
    int hidx = lane >> 4, cidx = lane & 15;
    float Rh = er[(long)n * H + hidx];
    int pd = pred[n];

    float4 acc = {0.f, 0.f, 0.f, 0.f};
    float dsum = 0.f, f1a = 0.f, ca = 0.f;

    for (int base = beg; base < end; base += 16) {
        int nk = end - base; if (nk > 16) nk = 16;
        float w = 0.f; int sp = 0;
        if (cidx < nk) {
            int s = ssrc[base + cidx];
            float x = el[(long)s * H + hidx] + Rh;
            x = x > 0.f ? x : 0.2f * x;
            w = __expf(x);
            if (hidx == 0) sp = s | (pred[s] << 16);
        }
        dsum += w;
        if (nk == 16) {
#pragma unroll
            for (int k = 0; k < 16; ++k) EDGE(k)
        } else {
            for (int k = 0; k < nk; ++k) EDGE(k)
        }
    }

    // per-head softmax denominator: reduce over the 16-lane group
    for (int off = 1; off < 16; off <<= 1) dsum += __shfl_xor(dsum, off);
    float invh = dsum > 0.f ? 1.f / dsum : 0.f;
    float invdeg = 1.0f / (float)(deg > 0 ? deg : 1);

    float4 o;
    o.x = acc.x * invh; o.y = acc.y * invh; o.z = acc.z * invh; o.w = acc.w * invh;
    *(float4*)(agg + (long)n * HD + (lane << 2)) = o;

    // f2 entropy term: lane (h,c) holds its class sum. (Globally-absent
    // classes contribute a constant that cancels in the global LayerNorm.)
    float v = fmaxf(ca * invh * invdeg, 1e-5f);
    float term = -v * logf(v);
    for (int off = 1; off < 16; off <<= 1) term += __shfl_xor(term, off);
    if (cidx == 0) {
        f1[(long)n * H + hidx] = f1a * invh * invdeg;
        f2[(long)n * H + hidx] = term;
    }
}

// single-block reduction of f1/f2 -> sums[4] (plain stores, deterministic)
__global__ __launch_bounds__(1024) void k_sum(const float* __restrict__ f1,
                                              const float* __restrict__ f2,
                                              float* __restrict__ sums) {
    __shared__ float red[16][4];
    float s1 = 0.f, q1 = 0.f, s2 = 0.f, q2 = 0.f;
    for (int i = threadIdx.x; i < NN * H; i += 1024) {
        float a = f1[i], b = f2[i];
        s1 += a; q1 = fmaf(a, a, q1);
        s2 += b; q2 = fmaf(b, b, q2);
    }
    for (int off = 32; off; off >>= 1) {
        s1 += __shfl_down(s1, off);
        q1 += __shfl_down(q1, off);
        s2 += __shfl_down(s2, off);
        q2 += __shfl_down(q2, off);
    }
    int wid = threadIdx.x >> 6;
    if ((threadIdx.x & 63) == 0) {
        red[wid][0] = s1; red[wid][1] = q1; red[wid][2] = s2; red[wid][3] = q2;
    }
    __syncthreads();
    if (threadIdx.x < 4) {
        float a = 0.f;
        for (int wv = 0; wv < 16; ++wv) a += red[wv][threadIdx.x];
        sums[threadIdx.x] = a;
    }
}

// fused: z/gate (LayerNorm'd f1,f2) + final output
__global__ __launch_bounds__(256) void k_out(const float* __restrict__ feat,
                                             const float* __restrict__ agg,
                                             const float* __restrict__ f1,
                                             const float* __restrict__ f2,
                                             const float* __restrict__ sums,
                                             const float* __restrict__ old_z,
                                             const float* __restrict__ tau1,
                                             const float* __restrict__ tau2,
                                             const int* __restrict__ rowptr,
                                             float* __restrict__ out,
                                             float* __restrict__ zout) {
    long i = (long)blockIdx.x * 256 + threadIdx.x;
    if (i >= (long)NN * HD) return;
    int n = (int)(i >> 8);
    int h = (int)((i >> 6) & 3);
    int t = n * H + h;
    constexpr float invNH = 1.0f / (NN * H);
    float mu1 = sums[0] * invNH, mu2 = sums[2] * invNH;
    float v1 = fmaxf(sums[1] * invNH - mu1 * mu1, 0.f);
    float v2 = fmaxf(sums[3] * invNH - mu2 * mu2, 0.f);
    float r1 = rsqrtf(v1 + 1e-5f), r2 = rsqrtf(v2 + 1e-5f);
    float nf1 = (f1[t] - mu1) * r1;
    float nf2 = (f2[t] - mu2) * r2;
    float z = (1.f / (1.f + expf(nf1 - tau1[0]))) * (1.f / (1.f + expf(nf2 - tau2[0])));
    float gate = fminf(old_z[t], z);
    if ((i & 63) == 0) zout[t] = z;
    int deg = rowptr[n + 1] - rowptr[n];
    float nrm = rsqrtf((float)(deg > 0 ? deg : 1));
    out[i] = feat[i] + gate * agg[i] * nrm;
}

extern "C" void kernel_launch(void* const* d_in, const int* in_sizes, int n_in,
                              void* d_out, int out_size, void* d_ws, size_t ws_size,
                              hipStream_t stream) {
    const float* hin    = (const float*)d_in[0];
    const float* logits = (const float*)d_in[1];
    const float* old_z  = (const float*)d_in[2];
    const float* attn_l = (const float*)d_in[3];
    const float* attn_r = (const float*)d_in[4];
    const float* Wfc    = (const float*)d_in[5];
    const float* tau1   = (const float*)d_in[6];
    const float* tau2   = (const float*)d_in[7];
    const int*   src    = (const int*)d_in[8];
    const int*   dst    = (const int*)d_in[9];
    float* out = (float*)d_out;
    float* ws  = (float*)d_ws;

    unsigned short* featb = (unsigned short*)(ws + OFF_FB);
    unsigned short* wp    = (unsigned short*)(ws + OFF_WP);
    unsigned short* ha    = (unsigned short*)(ws + OFF_HA);
    int* pred   = (int*)(ws + OFF_PRED);
    int* ssrc   = (int*)(ws + OFF_SSRC);
    int* rowptr = (int*)(ws + OFF_ROWP);
    int* cursor = (int*)(ws + OFF_CURS);
    int* deg_i  = (int*)(ws + OFF_DEGI);
    float* sums = ws + OFF_SUM;

    k_pack   <<<32 + ZB + HAB, 256, 0, stream>>>(Wfc, hin, wp, ha, deg_i);
    k_main   <<<GEMB + PB + CB, 256, 0, stream>>>(ha, wp, attn_l, attn_r, logits, dst,
                                                  ws + OFF_FEAT, featb,
                                                  ws + OFF_EL, ws + OFF_ER,
                                                  pred, deg_i);
    k_scan   <<<1, 1024, 0, stream>>>(deg_i, rowptr, cursor);
    k_scatter<<<(EE + 255) / 256, 256, 0, stream>>>(src, dst, cursor, ssrc);
    k_agg    <<<NN / 4, 256, 0, stream>>>(rowptr, ssrc, ws + OFF_EL, ws + OFF_ER,
                                          featb, pred,
                                          ws + OFF_AGG, ws + OFF_F1, ws + OFF_F2);
    k_sum    <<<1, 1024, 0, stream>>>(ws + OFF_F1, ws + OFF_F2, sums);
    k_out    <<<(NN * HD + 255) / 256, 256, 0, stream>>>(ws + OFF_FEAT, ws + OFF_AGG,
                                                         ws + OFF_F1, ws + OFF_F2, sums,
                                                         old_z, tau1, tau2, rowptr,
                                                         out, out + (long)NN * HD);
}

// Round 11
// 93.702 us; speedup vs baseline: 14.1604x; 1.2609x over previous
//
#include <hip/hip_runtime.h>
#include <math.h>

constexpr int NN = 10000;
constexpr int EE = 320000;
constexpr int H  = 4;
constexpr int D  = 64;
constexpr int C  = 16;
constexpr int IN = 256;
constexpr int HD = H * D; // 256

typedef __attribute__((ext_vector_type(8))) short bf16x8;
typedef __attribute__((ext_vector_type(4))) float f32x4;

__device__ __forceinline__ unsigned short f2b(float x) {
    unsigned int b = __float_as_uint(x);
    return (unsigned short)((b + 0x7FFFu + ((b >> 16) & 1u)) >> 16); // RNE bf16
}

// ---- workspace layout (float-element offsets) ----
constexpr long OFF_FEAT = 0;                               // N*HD f32
constexpr long OFF_FB   = OFF_FEAT + (long)NN * HD;        // N*HD bf16 = N*HD/2 floats
constexpr long OFF_EL   = OFF_FB   + (long)NN * HD / 2;    // N*H
constexpr long OFF_ER   = OFF_EL   + (long)NN * H;         // N*H
constexpr long OFF_F1   = OFF_ER   + (long)NN * H;         // N*H
constexpr long OFF_F2   = OFF_F1   + (long)NN * H;         // N*H
constexpr long OFF_AGG  = OFF_F2   + (long)NN * H;         // N*HD
constexpr long OFF_PRED = OFF_AGG  + (long)NN * HD;        // N   (int)
constexpr long OFF_SSRC = OFF_PRED + (long)NN;             // E   (int) src sorted by dst
constexpr long OFF_ROWP = OFF_SSRC + (long)EE;             // N+1 (int)
constexpr long OFF_RANK = OFF_ROWP + (long)NN + 1;         // E   (int) per-edge rank in dst
constexpr long OFF_DEGI = OFF_RANK + (long)EE;             // N   (int, zeroed by k_pack)
constexpr long OFF_SUM  = OFF_DEGI + (long)NN;             // 4 f32 (plain-stored by k_sum)
constexpr long OFF_WP   = OFF_SUM  + 4;                    // 65536 bf16 = 32768 floats
constexpr long OFF_HA   = OFF_WP   + 32768;                // N*IN bf16 A-frag table = 1.28M floats
constexpr long WS_END   = OFF_HA + (long)NN * IN / 2;

constexpr int GEMB = NN / 16;          // 625 MFMA-gemm blocks (16 rows each, exact)
constexpr int PB   = (NN + 255) / 256; // 40 pred blocks
constexpr int CB   = (EE + 255) / 256; // 1250 count blocks
constexpr int ZB   = (NN + 255) / 256; // 40 zero blocks (in k_pack)
constexpr int HAB  = (NN / 16) * 8 * 64 / 256; // 1250 ha-transform blocks

// k_pack roles: [0,32) W->B-fragment pack; [32,32+ZB) zero deg_i;
// [32+ZB, ...) h -> bf16 A-fragment table ha.
// ha[((tile*8 + ks)*64 + l)*8 + i] = bf16(h[tile*16 + (l&15)][ks*32 + (l>>4)*8 + i])
__global__ __launch_bounds__(256) void k_pack(const float* __restrict__ W,
                                              const float* __restrict__ hin,
                                              unsigned short* __restrict__ wp,
                                              unsigned short* __restrict__ ha,
                                              int* __restrict__ deg_i) {
    int bid = blockIdx.x;
    int t = threadIdx.x;
    if (bid < 32) {
        int tg = bid * 256 + t; // [0, 8192)
        int l  = tg & 63;
        int ct = (tg >> 6) & 3;
        int ks = (tg >> 8) & 7;
        int w  = tg >> 11;
        int col = w * 64 + ct * 16 + (l & 15);
        int kb  = ks * 32 + (l >> 4) * 8;
        unsigned short v[8];
#pragma unroll
        for (int i = 0; i < 8; ++i) v[i] = f2b(W[(long)(kb + i) * HD + col]);
        ushort4* p = (ushort4*)(wp + (long)tg * 8);
        p[0] = make_ushort4(v[0], v[1], v[2], v[3]);
        p[1] = make_ushort4(v[4], v[5], v[6], v[7]);
    } else if (bid < 32 + ZB) {
        int n = (bid - 32) * 256 + t;
        if (n < NN) deg_i[n] = 0;
    } else {
        int e = (bid - 32 - ZB) * 256 + t; // [0, 320000) exact
        int l = e & 63, ks = (e >> 6) & 7, tile = e >> 9;
        int row = tile * 16 + (l & 15);
        int k0  = ks * 32 + (l >> 4) * 8;
        const float* ap = hin + (long)row * IN + k0;
        float4 a0 = *(const float4*)(ap);
        float4 a1 = *(const float4*)(ap + 4);
        ushort4* p = (ushort4*)(ha + (long)e * 8);
        p[0] = make_ushort4(f2b(a0.x), f2b(a0.y), f2b(a0.z), f2b(a0.w));
        p[1] = make_ushort4(f2b(a1.x), f2b(a1.y), f2b(a1.z), f2b(a1.w));
    }
}

// fused main kernel: blocks [0,GEMB) MFMA gemm, [GEMB,GEMB+PB) pred, rest
// count+rank (the count atomic's return value IS the edge's slot rank,
// making the later scatter atomic-free).
__global__ __launch_bounds__(256) void k_main(const unsigned short* __restrict__ ha,
                                              const unsigned short* __restrict__ wp,
                                              const float* __restrict__ al,
                                              const float* __restrict__ ar,
                                              const float* __restrict__ logits,
                                              const int*   __restrict__ dst,
                                              float* __restrict__ feat,
                                              unsigned short* __restrict__ featb,
                                              float* __restrict__ el,
                                              float* __restrict__ er,
                                              int*   __restrict__ pred,
                                              int*   __restrict__ deg_i,
                                              int*   __restrict__ rank) {
    int bid = blockIdx.x;
    int t = threadIdx.x;
    if (bid < GEMB) {
        int tile = bid;
        int w = t >> 6, l = t & 63;
        int g = l >> 4, fr = l & 15;

        f32x4 acc[4];
#pragma unroll
        for (int ct = 0; ct < 4; ++ct) acc[ct] = (f32x4){0.f, 0.f, 0.f, 0.f};

        const unsigned short* wpw = wp + (long)w * 8 * 4 * 64 * 8;
        const unsigned short* hap = ha + (long)tile * 8 * 64 * 8;

        for (int ks = 0; ks < 8; ++ks) {
            bf16x8 af = *(const bf16x8*)(hap + ((long)ks * 64 + l) * 8);
#pragma unroll
            for (int ct = 0; ct < 4; ++ct) {
                bf16x8 bfr = *(const bf16x8*)(wpw + (((long)ks * 4 + ct) * 64 + l) * 8);
                acc[ct] = __builtin_amdgcn_mfma_f32_16x16x32_bf16(af, bfr, acc[ct], 0, 0, 0);
            }
        }

        float aLr[4], aRr[4];
#pragma unroll
        for (int ct = 0; ct < 4; ++ct) {
            aLr[ct] = al[w * 64 + ct * 16 + fr];
            aRr[ct] = ar[w * 64 + ct * 16 + fr];
        }
#pragma unroll
        for (int j = 0; j < 4; ++j) {
            int row = tile * 16 + g * 4 + j;
            float vl = 0.f, vr = 0.f;
#pragma unroll
            for (int ct = 0; ct < 4; ++ct) {
                float v = acc[ct][j];
                feat [(long)row * HD + w * 64 + ct * 16 + fr] = v;
                featb[(long)row * HD + w * 64 + ct * 16 + fr] = f2b(v);
                vl = fmaf(v, aLr[ct], vl);
                vr = fmaf(v, aRr[ct], vr);
            }
            vl += __shfl_xor(vl, 1); vl += __shfl_xor(vl, 2);
            vl += __shfl_xor(vl, 4); vl += __shfl_xor(vl, 8);
            vr += __shfl_xor(vr, 1); vr += __shfl_xor(vr, 2);
            vr += __shfl_xor(vr, 4); vr += __shfl_xor(vr, 8);
            if (fr == 0) {
                el[(long)row * H + w] = vl;
                er[(long)row * H + w] = vr;
            }
        }
    } else if (bid < GEMB + PB) {
        // ---- pred = argmax(logits) ----
        int n = (bid - GEMB) * 256 + t;
        if (n < NN) {
            const float* row = logits + (long)n * C;
            float best = row[0]; int bi = 0;
#pragma unroll
            for (int c = 1; c < C; ++c) { float v = row[c]; if (v > best) { best = v; bi = c; } }
            pred[n] = bi;
        }
    } else {
        // ---- in-degree counting; atomic return value = slot rank ----
        int e = (bid - GEMB - PB) * 256 + t;
        if (e < EE) rank[e] = atomicAdd(&deg_i[dst[e]], 1);
    }
}

// 1024-thread single-block exclusive scan -> rowptr. Shfl wave scans,
// only 2 barriers (replaces 20-barrier Hillis-Steele version).
__global__ __launch_bounds__(1024) void k_scan(const int* __restrict__ deg_i,
                                               int* __restrict__ rowptr) {
    __shared__ int wsum[16];
    constexpr int CH = (NN + 1023) / 1024; // 10
    int t = threadIdx.x;
    int lane = t & 63, wid = t >> 6;
    int base = t * CH;
    int d[CH];
    int s = 0;
#pragma unroll
    for (int i = 0; i < CH; ++i) {
        int idx = base + i;
        d[i] = (idx < NN) ? deg_i[idx] : 0;
        s += d[i];
    }
    // wave-level inclusive scan of per-thread sums
    int incl = s;
    for (int off = 1; off < 64; off <<= 1) {
        int v = __shfl_up(incl, off);
        if (lane >= off) incl += v;
    }
    if (lane == 63) wsum[wid] = incl;
    __syncthreads();
    if (t < 16) {
        int v = wsum[t];
        int inc2 = v;
        for (int off = 1; off < 16; off <<= 1) {
            int u = __shfl_up(inc2, off);
            if (t >= off) inc2 += u;
        }
        wsum[t] = inc2 - v; // exclusive offset for wave t
    }
    __syncthreads();
    int run = wsum[wid] + incl - s; // global exclusive prefix for this thread
#pragma unroll
    for (int i = 0; i < CH; ++i) {
        int idx = base + i;
        if (idx < NN) { rowptr[idx] = run; run += d[i]; }
    }
    if (t == 1023) rowptr[NN] = run; // == EE
}

// atomic-free scatter: slot = rowptr[dst] + rank (unique by construction)
__global__ __launch_bounds__(256) void k_scatter(const int* __restrict__ src,
                                                 const int* __restrict__ dst,
                                                 const int* __restrict__ rank,
                                                 const int* __restrict__ rowptr,
                                                 int* __restrict__ ssrc) {
    int e = blockIdx.x * 256 + threadIdx.x;
    if (e >= EE) return;
    ssrc[rowptr[dst[e]] + rank[e]] = src[e];
}

// one wave per dst node. 16-edge strips; per-edge (src,pred) broadcast via
// readlane (scalar-uniform gather address) + 1 shfl for the weight.
// feat gathered in bf16 (512B/row) to halve L2-miss traffic.
#define EDGE(kk) { \
    int spk = __builtin_amdgcn_readlane(sp, (kk)); \
    int s_  = spk & 0xFFFF; \
    int ps_ = spk >> 16; \
    float wa = __shfl(w, (hidx << 4) | (kk)); \
    const ushort4 f = *(const ushort4*)(featb + (long)s_ * HD + (lane << 2)); \
    acc.x = fmaf(wa, __uint_as_float((unsigned int)f.x << 16), acc.x); \
    acc.y = fmaf(wa, __uint_as_float((unsigned int)f.y << 16), acc.y); \
    acc.z = fmaf(wa, __uint_as_float((unsigned int)f.z << 16), acc.z); \
    acc.w = fmaf(wa, __uint_as_float((unsigned int)f.w << 16), acc.w); \
    f1a += (ps_ == pd)   ? wa : 0.f; \
    ca  += (ps_ == cidx) ? wa : 0.f; \
}

__global__ __launch_bounds__(256) void k_agg(const int* __restrict__ rowptr,
                                             const int* __restrict__ ssrc,
                                             const float* __restrict__ el,
                                             const float* __restrict__ er,
                                             const unsigned short* __restrict__ featb,
                                             const int* __restrict__ pred,
                                             float* __restrict__ agg,
                                             float* __restrict__ f1,
                                             float* __restrict__ f2) {
    int lane = threadIdx.x & 63;
    int n = blockIdx.x * 4 + (threadIdx.x >> 6); // grid = NN/4 exactly
    int beg = rowptr[n], end = rowptr[n + 1];
    int deg = end - beg;
    int hidx = lane >> 4, cidx = lane & 15;
    float Rh = er[(long)n * H + hidx];
    int pd = pred[n];

    float4 acc = {0.f, 0.f, 0.f, 0.f};
    float dsum = 0.f, f1a = 0.f, ca = 0.f;

    for (int base = beg; base < end; base += 16) {
        int nk = end - base; if (nk > 16) nk = 16;
        float w = 0.f; int sp = 0;
        if (cidx < nk) {
            int s = ssrc[base + cidx];
            float x = el[(long)s * H + hidx] + Rh;
            x = x > 0.f ? x : 0.2f * x;
            w = __expf(x);
            if (hidx == 0) sp = s | (pred[s] << 16);
        }
        dsum += w;
        if (nk == 16) {
#pragma unroll
            for (int k = 0; k < 16; ++k) EDGE(k)
        } else {
            for (int k = 0; k < nk; ++k) EDGE(k)
        }
    }

    // per-head softmax denominator: reduce over the 16-lane group
    for (int off = 1; off < 16; off <<= 1) dsum += __shfl_xor(dsum, off);
    float invh = dsum > 0.f ? 1.f / dsum : 0.f;
    float invdeg = 1.0f / (float)(deg > 0 ? deg : 1);

    float4 o;
    o.x = acc.x * invh; o.y = acc.y * invh; o.z = acc.z * invh; o.w = acc.w * invh;
    *(float4*)(agg + (long)n * HD + (lane << 2)) = o;

    // f2 entropy term: lane (h,c) holds its class sum. (Globally-absent
    // classes contribute a constant that cancels in the global LayerNorm.)
    float v = fmaxf(ca * invh * invdeg, 1e-5f);
    float term = -v * logf(v);
    for (int off = 1; off < 16; off <<= 1) term += __shfl_xor(term, off);
    if (cidx == 0) {
        f1[(long)n * H + hidx] = f1a * invh * invdeg;
        f2[(long)n * H + hidx] = term;
    }
}

// single-block reduction of f1/f2 -> sums[4] (plain stores, deterministic)
__global__ __launch_bounds__(1024) void k_sum(const float* __restrict__ f1,
                                              const float* __restrict__ f2,
                                              float* __restrict__ sums) {
    __shared__ float red[16][4];
    float s1 = 0.f, q1 = 0.f, s2 = 0.f, q2 = 0.f;
    for (int i = threadIdx.x; i < NN * H; i += 1024) {
        float a = f1[i], b = f2[i];
        s1 += a; q1 = fmaf(a, a, q1);
        s2 += b; q2 = fmaf(b, b, q2);
    }
    for (int off = 32; off; off >>= 1) {
        s1 += __shfl_down(s1, off);
        q1 += __shfl_down(q1, off);
        s2 += __shfl_down(s2, off);
        q2 += __shfl_down(q2, off);
    }
    int wid = threadIdx.x >> 6;
    if ((threadIdx.x & 63) == 0) {
        red[wid][0] = s1; red[wid][1] = q1; red[wid][2] = s2; red[wid][3] = q2;
    }
    __syncthreads();
    if (threadIdx.x < 4) {
        float a = 0.f;
        for (int wv = 0; wv < 16; ++wv) a += red[wv][threadIdx.x];
        sums[threadIdx.x] = a;
    }
}

// fused: z/gate (LayerNorm'd f1,f2) + final output
__global__ __launch_bounds__(256) void k_out(const float* __restrict__ feat,
                                             const float* __restrict__ agg,
                                             const float* __restrict__ f1,
                                             const float* __restrict__ f2,
                                             const float* __restrict__ sums,
                                             const float* __restrict__ old_z,
                                             const float* __restrict__ tau1,
                                             const float* __restrict__ tau2,
                                             const int* __restrict__ rowptr,
                                             float* __restrict__ out,
                                             float* __restrict__ zout) {
    long i = (long)blockIdx.x * 256 + threadIdx.x;
    if (i >= (long)NN * HD) return;
    int n = (int)(i >> 8);
    int h = (int)((i >> 6) & 3);
    int t = n * H + h;
    constexpr float invNH = 1.0f / (NN * H);
    float mu1 = sums[0] * invNH, mu2 = sums[2] * invNH;
    float v1 = fmaxf(sums[1] * invNH - mu1 * mu1, 0.f);
    float v2 = fmaxf(sums[3] * invNH - mu2 * mu2, 0.f);
    float r1 = rsqrtf(v1 + 1e-5f), r2 = rsqrtf(v2 + 1e-5f);
    float nf1 = (f1[t] - mu1) * r1;
    float nf2 = (f2[t] - mu2) * r2;
    float z = (1.f / (1.f + expf(nf1 - tau1[0]))) * (1.f / (1.f + expf(nf2 - tau2[0])));
    float gate = fminf(old_z[t], z);
    if ((i & 63) == 0) zout[t] = z;
    int deg = rowptr[n + 1] - rowptr[n];
    float nrm = rsqrtf((float)(deg > 0 ? deg : 1));
    out[i] = feat[i] + gate * agg[i] * nrm;
}

extern "C" void kernel_launch(void* const* d_in, const int* in_sizes, int n_in,
                              void* d_out, int out_size, void* d_ws, size_t ws_size,
                              hipStream_t stream) {
    const float* hin    = (const float*)d_in[0];
    const float* logits = (const float*)d_in[1];
    const float* old_z  = (const float*)d_in[2];
    const float* attn_l = (const float*)d_in[3];
    const float* attn_r = (const float*)d_in[4];
    const float* Wfc    = (const float*)d_in[5];
    const float* tau1   = (const float*)d_in[6];
    const float* tau2   = (const float*)d_in[7];
    const int*   src    = (const int*)d_in[8];
    const int*   dst    = (const int*)d_in[9];
    float* out = (float*)d_out;
    float* ws  = (float*)d_ws;

    unsigned short* featb = (unsigned short*)(ws + OFF_FB);
    unsigned short* wp    = (unsigned short*)(ws + OFF_WP);
    unsigned short* ha    = (unsigned short*)(ws + OFF_HA);
    int* pred   = (int*)(ws + OFF_PRED);
    int* ssrc   = (int*)(ws + OFF_SSRC);
    int* rowptr = (int*)(ws + OFF_ROWP);
    int* rank   = (int*)(ws + OFF_RANK);
    int* deg_i  = (int*)(ws + OFF_DEGI);
    float* sums = ws + OFF_SUM;

    k_pack   <<<32 + ZB + HAB, 256, 0, stream>>>(Wfc, hin, wp, ha, deg_i);
    k_main   <<<GEMB + PB + CB, 256, 0, stream>>>(ha, wp, attn_l, attn_r, logits, dst,
                                                  ws + OFF_FEAT, featb,
                                                  ws + OFF_EL, ws + OFF_ER,
                                                  pred, deg_i, rank);
    k_scan   <<<1, 1024, 0, stream>>>(deg_i, rowptr);
    k_scatter<<<(EE + 255) / 256, 256, 0, stream>>>(src, dst, rank, rowptr, ssrc);
    k_agg    <<<NN / 4, 256, 0, stream>>>(rowptr, ssrc, ws + OFF_EL, ws + OFF_ER,
                                          featb, pred,
                                          ws + OFF_AGG, ws + OFF_F1, ws + OFF_F2);
    k_sum    <<<1, 1024, 0, stream>>>(ws + OFF_F1, ws + OFF_F2, sums);
    k_out    <<<(NN * HD + 255) / 256, 256, 0, stream>>>(ws + OFF_FEAT, ws + OFF_AGG,
                                                         ws + OFF_F1, ws + OFF_F2, sums,
                                                         old_z, tau1, tau2, rowptr,
                                                         out, out + (long)NN * HD);
}